// Round 8
// baseline (1809.491 us; speedup 1.0000x reference)
//
#include <hip/hip_runtime.h>
#include <hip/hip_bf16.h>

typedef unsigned short u16;
typedef unsigned int u32;
typedef unsigned long long u64;
typedef __attribute__((ext_vector_type(8))) short short8;
typedef __attribute__((ext_vector_type(4))) float f32x4;

#define NB 256
#define NT 512          // 8 waves
#define TS 128
#define LDK 136         // 128 + 8 bf16 pad

// d_out offsets (floats): [out][h_n0][h_n1][c_n0][c_n1]
#define OFF_H0  786432
#define OFF_H1  1048576
#define OFF_C0  1114112
#define OFF_C1  1376256

// ws offsets (bytes)
#define WSO_W0F  0                         // 10240 frags x 1KB
#define WSO_W1F  (WSO_W0F + 10485760)      // 2560 frags x 1KB
#define WSO_B0   (WSO_W1F + 2621440)
#define WSO_B1   (WSO_B0  + 16384)
#define WSO_H0   (WSO_B1  + 4096)          // 2 x [256][1024] bf16
#define WSO_H1   (WSO_H0  + 1048576)       // 2 x [256][256]
#define WSO_X    (WSO_H1  + 262144)        // 2 x [256][256]
#define WSO_HSEQ (WSO_X   + 262144)        // [128][256][256] f32
#define WSO_BAR  (WSO_HSEQ + 33554432)
// flags: 256 x 16dw lines; rel: 4 x 16dw lines at dw 4096
#define BAR_DW   (4096 + 64)
#define WS_NEED  (WSO_BAR + BAR_DW*4)

struct MP {
  const float* x;
  const u16*  W0F;      // layer0 weights, MFMA-fragment layout
  const u16*  W1F;      // layer1 weights, MFMA-fragment layout
  const float* b0;      // [4096] n=h*4+g
  const float* b1;      // [1024]
  u16*  H0;             // 2 x [256][1024]
  u16*  H1;             // 2 x [256][256]
  u16*  X;              // 2 x [256][256]
  float* hseq;          // [128][256][256]
  float* out;
  unsigned* bar;
};

__device__ __forceinline__ float sigm(float x){ return 1.f/(1.f+__expf(-x)); }
__device__ __forceinline__ float tanh_(float x){
  float t = __expf(-2.f*fabsf(x));
  float r = (1.f - t)/(1.f + t);
  return x < 0.f ? -r : r;
}
__device__ __forceinline__ u16 f2b(float v){
  __hip_bfloat16 h = __float2bfloat16(v);
  return *reinterpret_cast<u16*>(&h);
}
__device__ __forceinline__ void ast32(u16* p, u32 v){
  __hip_atomic_store((u32*)p, v, __ATOMIC_RELAXED, __HIP_MEMORY_SCOPE_AGENT);
}
__device__ __forceinline__ f32x4 MF(short8 a, short8 b, f32x4 c){
  return __builtin_amdgcn_mfma_f32_16x16x32_bf16(a, b, c, 0, 0, 0);
}

#define STRX(x) #x
#define PLOADO(dst, ptr, off) asm volatile("global_load_dwordx4 %0, %1, off offset:" STRX(off) : "=v"(dst) : "v"(ptr))
#define CLOADO(dst, ptr, off) asm volatile("global_load_dwordx4 %0, %1, off offset:" STRX(off) " sc0 sc1" : "=v"(dst) : "v"(ptr))
__device__ __forceinline__ void cwait(){
  asm volatile("s_waitcnt vmcnt(0)" ::: "memory");
  __builtin_amdgcn_sched_barrier(0);
}

// ---------------- prologue kernels ----------------

// layer0 frag F = ((nt*10+kt)*4+wn)*8 + nf*4+kk ; lane -> n=(lane&15), k-sub=(lane>>4)*8
__global__ void k_packF0(const float* __restrict__ Wx, const float* __restrict__ Wh,
                         u16* __restrict__ W0F){
  int gid = blockIdx.x*256 + threadIdx.x;       // 655360
  int F = gid >> 6, lane = gid & 63;
  int kk = F & 3, nf = (F >> 2) & 1;
  int r1 = F >> 3, wn = r1 & 3;
  int r2 = r1 >> 2, kt = r2 % 10, nt = r2 / 10; // nt 0..31
  int n = nt*128 + wn*32 + nf*16 + (lane & 15);
  int h = n >> 2, g = n & 3;
  int kb = kt*128 + kk*32 + (lane >> 4)*8;
  union { u16 u[8]; short8 v; } pk;
#pragma unroll
  for (int j = 0; j < 8; ++j) {
    int k = kb + j;
    float v = (k < 256) ? Wx[((size_t)g*256 + k)*1024 + h]
                        : Wh[((size_t)g*1024 + (k-256))*1024 + h];
    pk.u[j] = f2b(v);
  }
  *(short8*)&W0F[(size_t)F*512 + lane*8] = pk.v;
}

// layer1 frag F = ((ntp*10+kt)*4+wn)*4 + kk
__global__ void k_packF1(const float* __restrict__ Wx, const float* __restrict__ Wh,
                         u16* __restrict__ W1F){
  int gid = blockIdx.x*256 + threadIdx.x;       // 163840
  int F = gid >> 6, lane = gid & 63;
  int kk = F & 3;
  int r1 = F >> 2, wn = r1 & 3;
  int r2 = r1 >> 2, kt = r2 % 10, ntp = r2 / 10; // ntp 0..15
  int n = ntp*64 + wn*16 + (lane & 15);
  int h = n >> 2, g = n & 3;
  int kb = kt*128 + kk*32 + (lane >> 4)*8;
  union { u16 u[8]; short8 v; } pk;
#pragma unroll
  for (int j = 0; j < 8; ++j) {
    int k = kb + j;
    float v = (k < 1024) ? Wx[((size_t)g*1024 + k)*256 + h]
                         : Wh[((size_t)g*256 + (k-1024))*256 + h];
    pk.u[j] = f2b(v);
  }
  *(short8*)&W1F[(size_t)F*512 + lane*8] = pk.v;
}

__global__ void k_bias(const float* __restrict__ bx0, const float* __restrict__ bh0,
                       const float* __restrict__ bx1, const float* __restrict__ bh1,
                       float* __restrict__ b0, float* __restrict__ b1){
  int n = blockIdx.x*256 + threadIdx.x;
  if (n < 4096) { int h = n >> 2, g = n & 3; b0[n] = bx0[g*1024 + h] + bh0[g*1024 + h]; }
  if (n < 1024) { int h = n >> 2, g = n & 3; b1[n] = bx1[g*256 + h] + bh1[g*256 + h]; }
}

__global__ void k_init(u16* __restrict__ H0, u16* __restrict__ H1,
                       unsigned* __restrict__ bar){
  int i = blockIdx.x*256 + threadIdx.x;         // 2048 blocks -> 524288
  if (i < 524288) H0[i] = 0;
  if (i < 131072) H1[i] = 0;
  if (i < BAR_DW) bar[i] = 0u;
}

__global__ void k_init2(const float* __restrict__ x, u16* __restrict__ X0){
  int i = blockIdx.x*256 + threadIdx.x;         // 65536
  X0[i] = f2b(x[(size_t)(i >> 8)*32768 + (i & 255)]);
}

// ------------- store/poll group barrier (no RMW serialization) -------------
// Worker: one relaxed sc1 store to its own 64B flag line, then poll release.
// Aggregator (first stage block of group): wave0 lane-parallel polls the 63
// peer flags, then stores the group release word. All relaxed; producer-side
// ordering comes from __syncthreads' vmcnt(0) drain (sc1 stores acked at the
// coherence point before the flag store issues).
__device__ __forceinline__ void gbar_worker(unsigned* flags, unsigned* rel,
                                            int bid, unsigned gen){
  __syncthreads();
  if (threadIdx.x == 0) {
    __hip_atomic_store(&flags[bid*16], gen, __ATOMIC_RELAXED, __HIP_MEMORY_SCOPE_AGENT);
    while (__hip_atomic_load(rel, __ATOMIC_RELAXED, __HIP_MEMORY_SCOPE_AGENT) < gen)
      __builtin_amdgcn_s_sleep(1);
  }
  __syncthreads();
}
__device__ __forceinline__ void gbar_agg(unsigned* flags, unsigned* rel,
                                         int grp, unsigned gen){
  __syncthreads();
  int tid = threadIdx.x;
  if (tid < 64) {
    int tb;
    if (tid < 32)      tb = grp*32 + tid;              // phase0 peers
    else if (tid < 48) tb = 128 + grp*16 + (tid - 32); // phase1 peers
    else if (tid < 63) tb = 193 + grp*16 + (tid - 48); // stage peers (skip self)
    else               tb = -1;
    unsigned v = gen;
    for (;;) {
      if (tb >= 0)
        v = __hip_atomic_load(&flags[tb*16], __ATOMIC_RELAXED, __HIP_MEMORY_SCOPE_AGENT);
      if (__all((int)(v >= gen))) break;
      __builtin_amdgcn_s_sleep(1);
    }
    if (tid == 0)
      __hip_atomic_store(rel, gen, __ATOMIC_RELAXED, __HIP_MEMORY_SCOPE_AGENT);
  }
  __syncthreads();
}

// ---------------- phase0: blocks 0..127, tile 64m x 128n, 8 waves 2x4 ------
__device__ void phase0(const MP& p, int t, char* smem, float* c0){
  const int bid = blockIdx.x, tid = threadIdx.x;
  const int xcd = bid & 7, local = (bid >> 3) & 3, grp = bid >> 5;
  const int nt = xcd*4 + local;         // 0..31
  const int m0 = grp*64, n0 = nt*128;
  const int lane = tid & 63, wid = tid >> 6;
  const int wm = wid >> 2, wn = wid & 3;
  const int lrow = lane & 15, kgrp = lane >> 4;
  u16* As = (u16*)smem;                 // [64][LDK]
  const u16* Xp = p.X  + (size_t)(t & 1)*65536;
  const u16* Hp = p.H0 + (size_t)(t & 1)*262144;
  const int ar = tid >> 3, s0 = (tid & 7)*2;
  const u16* bbase = p.W0F + (size_t)(nt*40 + wn)*4096 + lane*8;

  auto aptr = [&](int kt)->const u16* {
    return (kt < 2) ? Xp + (size_t)(m0+ar)*256  + kt*128       + s0*8
                    : Hp + (size_t)(m0+ar)*1024 + (kt-2)*128   + s0*8;
  };
  auto bptr = [&](int kt)->const u16* { return bbase + (size_t)kt*16384; };

  short8 raa0, raa1, rab0, rab1;
  short8 rba0, rba1, rba2, rba3, rba4, rba5, rba6, rba7;
  short8 rbb0, rbb1, rbb2, rbb3, rbb4, rbb5, rbb6, rbb7;
  f32x4 acc00 = {0,0,0,0}, acc01 = {0,0,0,0}, acc10 = {0,0,0,0}, acc11 = {0,0,0,0};

#define ISS_A2(PTR, R0,R1) do{ const u16* _s=(PTR); CLOADO(R0,_s,0); CLOADO(R1,_s,16); }while(0)
#define ST_A2(R0,R1) do{ u16* _d = As + ar*LDK + s0*8; \
    *(short8*)&_d[0]=R0; *(short8*)&_d[8]=R1; }while(0)
#define ISS_B8(PTR, R0,R1,R2,R3,R4,R5,R6,R7) do{ const u16* _s=(PTR); const u16* _s2=_s+2048; \
    PLOADO(R0,_s,0); PLOADO(R1,_s,1024); PLOADO(R2,_s,2048); PLOADO(R3,_s,3072); \
    PLOADO(R4,_s2,0); PLOADO(R5,_s2,1024); PLOADO(R6,_s2,2048); PLOADO(R7,_s2,3072); }while(0)
#define MFMA_P0(B0,B1,B2,B3,B4,B5,B6,B7) do{ short8 a0, a1; \
    a0 = *(const short8*)&As[(wm*32      + lrow)*LDK +  0 + kgrp*8]; \
    a1 = *(const short8*)&As[(wm*32 + 16 + lrow)*LDK +  0 + kgrp*8]; \
    acc00 = MF(a0,B0,acc00); acc01 = MF(a0,B4,acc01); acc10 = MF(a1,B0,acc10); acc11 = MF(a1,B4,acc11); \
    a0 = *(const short8*)&As[(wm*32      + lrow)*LDK + 32 + kgrp*8]; \
    a1 = *(const short8*)&As[(wm*32 + 16 + lrow)*LDK + 32 + kgrp*8]; \
    acc00 = MF(a0,B1,acc00); acc01 = MF(a0,B5,acc01); acc10 = MF(a1,B1,acc10); acc11 = MF(a1,B5,acc11); \
    a0 = *(const short8*)&As[(wm*32      + lrow)*LDK + 64 + kgrp*8]; \
    a1 = *(const short8*)&As[(wm*32 + 16 + lrow)*LDK + 64 + kgrp*8]; \
    acc00 = MF(a0,B2,acc00); acc01 = MF(a0,B6,acc01); acc10 = MF(a1,B2,acc10); acc11 = MF(a1,B6,acc11); \
    a0 = *(const short8*)&As[(wm*32      + lrow)*LDK + 96 + kgrp*8]; \
    a1 = *(const short8*)&As[(wm*32 + 16 + lrow)*LDK + 96 + kgrp*8]; \
    acc00 = MF(a0,B3,acc00); acc01 = MF(a0,B7,acc01); acc10 = MF(a1,B3,acc10); acc11 = MF(a1,B7,acc11); }while(0)

  ISS_A2(aptr(0), raa0,raa1);
  ISS_B8(bptr(0), rba0,rba1,rba2,rba3,rba4,rba5,rba6,rba7);
  for (int k2 = 0; k2 < 5; ++k2) {
    const int kto = 2*k2 + 1;
    // even sub-iter
    cwait();                 // raa (A tile) + rba (B frags) ready
    __syncthreads();         // prior MFMA reads of As done
    ST_A2(raa0,raa1);
    __syncthreads();         // A tile visible (drains lgkm)
    ISS_A2(aptr(kto), rab0,rab1);
    ISS_B8(bptr(kto), rbb0,rbb1,rbb2,rbb3,rbb4,rbb5,rbb6,rbb7);
    MFMA_P0(rba0,rba1,rba2,rba3,rba4,rba5,rba6,rba7);
    // odd sub-iter
    cwait();
    __syncthreads();
    ST_A2(rab0,rab1);
    __syncthreads();
    if (kto < 9) {
      ISS_A2(aptr(kto+1), raa0,raa1);
      ISS_B8(bptr(kto+1), rba0,rba1,rba2,rba3,rba4,rba5,rba6,rba7);
    }
    MFMA_P0(rbb0,rbb1,rbb2,rbb3,rbb4,rbb5,rbb6,rbb7);
  }
  __syncthreads();           // all MFMA LDS reads done before gl aliasing

  float* gl = (float*)smem;  // [64][132]
#pragma unroll
  for (int r = 0; r < 4; ++r) {
    gl[(wm*32      + kgrp*4 + r)*132 + wn*32      + lrow] = acc00[r];
    gl[(wm*32      + kgrp*4 + r)*132 + wn*32 + 16 + lrow] = acc01[r];
    gl[(wm*32 + 16 + kgrp*4 + r)*132 + wn*32      + lrow] = acc10[r];
    gl[(wm*32 + 16 + kgrp*4 + r)*132 + wn*32 + 16 + lrow] = acc11[r];
  }
  __syncthreads();
  u16* H0n = p.H0 + (size_t)((t+1) & 1)*262144;
#pragma unroll
  for (int rep = 0; rep < 2; ++rep) {
    int e = tid + rep*NT;
    int bl = e >> 4, hp = e & 15;
    int b = m0 + bl, h = nt*32 + hp*2;
    float hn[2];
#pragma unroll
    for (int q = 0; q < 2; ++q) {
      int col = (hp*2 + q)*4;
      float gi = gl[bl*132 + col+0] + p.b0[n0 + col+0];
      float gf = gl[bl*132 + col+1] + p.b0[n0 + col+1];
      float go = gl[bl*132 + col+2] + p.b0[n0 + col+2];
      float gc = gl[bl*132 + col+3] + p.b0[n0 + col+3];
      float cn = sigm(gf)*c0[rep*2+q] + sigm(gi)*tanh_(gc);
      hn[q] = sigm(go)*tanh_(cn);
      c0[rep*2+q] = cn;
      if (t == TS-1) {
        p.out[OFF_H0 + (size_t)b*1024 + h + q] = hn[q];
        p.out[OFF_C0 + (size_t)b*1024 + h + q] = cn;
      }
    }
    ast32(H0n + (size_t)b*1024 + h, (u32)f2b(hn[0]) | ((u32)f2b(hn[1]) << 16));
  }
}

// ---------------- phase1: blocks 128..191, tile 64m x 64n, 8 waves 2x4 -----
__device__ void phase1(const MP& p, int t, char* smem, float* c1){
  const int tid = threadIdx.x;
  const int j = blockIdx.x - 128;
  const int xcd = j & 7, local = (j >> 3) & 1, grp = j >> 4;
  const int ntp = xcd*2 + local;        // 0..15
  const int m0 = grp*64, n0 = ntp*64;
  const int lane = tid & 63, wid = tid >> 6;
  const int wm = wid >> 2, wn = wid & 3;
  const int lrow = lane & 15, kgrp = lane >> 4;
  u16* As = (u16*)smem;                 // [64][LDK]
  const u16* Hp  = p.H0 + (size_t)((t+1) & 1)*262144;  // h0(t)
  const u16* H1p = p.H1 + (size_t)(t & 1)*65536;       // h1(t-1)
  const int ar = tid >> 3, s0 = (tid & 7)*2;
  const u16* bbase = p.W1F + (size_t)(ntp*40 + wn)*2048 + lane*8;

  auto aptr = [&](int kt)->const u16* {
    return (kt < 8) ? Hp  + (size_t)(m0+ar)*1024 + kt*128     + s0*8
                    : H1p + (size_t)(m0+ar)*256  + (kt-8)*128 + s0*8;
  };
  auto bptr = [&](int kt)->const u16* { return bbase + (size_t)kt*8192; };

  short8 raa0, raa1, rab0, rab1;
  short8 rba0, rba1, rba2, rba3, rbb0, rbb1, rbb2, rbb3;
  f32x4 acc0 = {0,0,0,0}, acc1 = {0,0,0,0};

#define ISS_B4(PTR, R0,R1,R2,R3) do{ const u16* _s=(PTR); \
    PLOADO(R0,_s,0); PLOADO(R1,_s,1024); PLOADO(R2,_s,2048); PLOADO(R3,_s,3072); }while(0)
#define MFMA_P1(B0,B1,B2,B3) do{ short8 a0, a1; \
    a0 = *(const short8*)&As[(wm*32      + lrow)*LDK +  0 + kgrp*8]; \
    a1 = *(const short8*)&As[(wm*32 + 16 + lrow)*LDK +  0 + kgrp*8]; \
    acc0 = MF(a0,B0,acc0); acc1 = MF(a1,B0,acc1); \
    a0 = *(const short8*)&As[(wm*32      + lrow)*LDK + 32 + kgrp*8]; \
    a1 = *(const short8*)&As[(wm*32 + 16 + lrow)*LDK + 32 + kgrp*8]; \
    acc0 = MF(a0,B1,acc0); acc1 = MF(a1,B1,acc1); \
    a0 = *(const short8*)&As[(wm*32      + lrow)*LDK + 64 + kgrp*8]; \
    a1 = *(const short8*)&As[(wm*32 + 16 + lrow)*LDK + 64 + kgrp*8]; \
    acc0 = MF(a0,B2,acc0); acc1 = MF(a1,B2,acc1); \
    a0 = *(const short8*)&As[(wm*32      + lrow)*LDK + 96 + kgrp*8]; \
    a1 = *(const short8*)&As[(wm*32 + 16 + lrow)*LDK + 96 + kgrp*8]; \
    acc0 = MF(a0,B3,acc0); acc1 = MF(a1,B3,acc1); }while(0)

  ISS_A2(aptr(0), raa0,raa1);
  ISS_B4(bptr(0), rba0,rba1,rba2,rba3);
  for (int k2 = 0; k2 < 5; ++k2) {
    const int kto = 2*k2 + 1;
    cwait();
    __syncthreads();
    ST_A2(raa0,raa1);
    __syncthreads();
    ISS_A2(aptr(kto), rab0,rab1);
    ISS_B4(bptr(kto), rbb0,rbb1,rbb2,rbb3);
    MFMA_P1(rba0,rba1,rba2,rba3);
    cwait();
    __syncthreads();
    ST_A2(rab0,rab1);
    __syncthreads();
    if (kto < 9) {
      ISS_A2(aptr(kto+1), raa0,raa1);
      ISS_B4(bptr(kto+1), rba0,rba1,rba2,rba3);
    }
    MFMA_P1(rbb0,rbb1,rbb2,rbb3);
  }
  __syncthreads();

  float* gl = (float*)smem;             // [64][68]
#pragma unroll
  for (int r = 0; r < 4; ++r) {
    gl[(wm*32      + kgrp*4 + r)*68 + wn*16 + lrow] = acc0[r];
    gl[(wm*32 + 16 + kgrp*4 + r)*68 + wn*16 + lrow] = acc1[r];
  }
  __syncthreads();
  u16* H1n = p.H1 + (size_t)((t+1) & 1)*65536;
  {
    int bl = tid >> 3, hp = tid & 7;    // 64 b-rows x 8 h-pairs
    int b = m0 + bl, h = ntp*16 + hp*2;
    float hn[2];
#pragma unroll
    for (int q = 0; q < 2; ++q) {
      int col = (hp*2 + q)*4;
      float gi = gl[bl*68 + col+0] + p.b1[n0 + col+0];
      float gf = gl[bl*68 + col+1] + p.b1[n0 + col+1];
      float go = gl[bl*68 + col+2] + p.b1[n0 + col+2];
      float gc = gl[bl*68 + col+3] + p.b1[n0 + col+3];
      float cn = sigm(gf)*c1[q] + sigm(gi)*tanh_(gc);
      hn[q] = sigm(go)*tanh_(cn);
      c1[q] = cn;
      if (t == TS-1) {
        p.out[OFF_H1 + (size_t)b*256 + h + q] = hn[q];
        p.out[OFF_C1 + (size_t)b*256 + h + q] = cn;
      }
    }
    ast32(H1n + (size_t)b*256 + h, (u32)f2b(hn[0]) | ((u32)f2b(hn[1]) << 16));
    *(float2*)&p.hseq[((size_t)t*256 + b)*256 + h] = make_float2(hn[0], hn[1]);
  }
}

// ---------------- stage blocks 192..255: pre-stage x_{tn} ------------------
__device__ void stage_x(const MP& p, int tn){
  int j = blockIdx.x - 192;
  int mt = j >> 4, j2 = j & 15;
  u16* Xn = p.X + (size_t)(tn & 1)*65536;
  int idx = j2*NT + threadIdx.x;        // 0..8191 f-pairs for 64 rows
  int bl = idx >> 7, fp = idx & 127;
  int b = mt*64 + bl;
  const float* xs = &p.x[(size_t)b*32768 + (size_t)tn*256 + fp*2];
  ast32(&Xn[b*256 + fp*2], (u32)f2b(xs[0]) | ((u32)f2b(xs[1]) << 16));
}

__global__ __launch_bounds__(NT) void k_main(MP p){
  __shared__ __attribute__((aligned(16))) char smem[34816];
  float c0[4] = {0.f, 0.f, 0.f, 0.f};
  float c1[2] = {0.f, 0.f};
  const int bid = blockIdx.x;
  const int grp = (bid < 128) ? (bid >> 5)
                : (bid < 192) ? ((bid - 128) >> 4)
                              : ((bid - 192) >> 4);
  unsigned* flags = p.bar;
  unsigned* rel   = p.bar + 4096 + grp*16;
  const bool agg = (bid >= 192) && (((bid - 192) & 15) == 0);
  for (int s = 0; s < TS; ++s) {
    if (bid < 128)        phase0(p, s, smem, c0);                  // layer0 @ t=s
    else if (bid < 192) { if (s >= 1) phase1(p, s-1, smem, c1); }  // layer1 @ t=s-1
    else                { if (s+1 < TS) stage_x(p, s+1); }
    if (agg) gbar_agg(flags, rel, grp, (unsigned)(s + 1));
    else     gbar_worker(flags, rel, bid, (unsigned)(s + 1));
  }
  if (bid >= 128 && bid < 192) phase1(p, TS-1, smem, c1);          // pipeline tail
}

// ---------------- final projection ----------------
__global__ void k_final(const float* __restrict__ hseq, const float* __restrict__ Wout,
                        const float* __restrict__ bout, float* __restrict__ out){
  __shared__ float Ws[1536];
  __shared__ float bs[12];
  for (int i = threadIdx.x; i < 1536; i += 256) Ws[i] = Wout[i];
  if (threadIdx.x < 12) bs[threadIdx.x] = bout[threadIdx.x];
  __syncthreads();
  int gid = blockIdx.x*256 + threadIdx.x;
  int b = gid >> 8, ii = gid & 255;
  const float* src = hseq + ((size_t)(ii >> 1)*256 + b)*256 + (ii & 1)*128;
  float acc[12];
#pragma unroll
  for (int k = 0; k < 12; ++k) acc[k] = bs[k];
  for (int jj = 0; jj < 128; jj += 4) {
    float4 v = *(const float4*)&src[jj];
#pragma unroll
    for (int k = 0; k < 12; ++k)
      acc[k] += v.x*Ws[(jj+0)*12+k] + v.y*Ws[(jj+1)*12+k] + v.z*Ws[(jj+2)*12+k] + v.w*Ws[(jj+3)*12+k];
  }
  float* dst = out + (size_t)b*3072 + ii*12;
#pragma unroll
  for (int k = 0; k < 12; ++k) dst[k] = acc[k];
}

extern "C" void kernel_launch(void* const* d_in, const int* in_sizes, int n_in,
                              void* d_out, int out_size, void* d_ws, size_t ws_size,
                              hipStream_t stream) {
  if (ws_size < (size_t)WS_NEED) return;
  const float* x    = (const float*)d_in[0];
  const float* Wx0  = (const float*)d_in[1];
  const float* bx0  = (const float*)d_in[2];
  const float* Wh0  = (const float*)d_in[3];
  const float* bh0  = (const float*)d_in[4];
  const float* Wx1  = (const float*)d_in[5];
  const float* bx1  = (const float*)d_in[6];
  const float* Wh1  = (const float*)d_in[7];
  const float* bh1  = (const float*)d_in[8];
  const float* Wout = (const float*)d_in[9];
  const float* bout = (const float*)d_in[10];

  char* ws = (char*)d_ws;
  u16*   W0F  = (u16*)  (ws + WSO_W0F);
  u16*   W1F  = (u16*)  (ws + WSO_W1F);
  float* b0   = (float*)(ws + WSO_B0);
  float* b1   = (float*)(ws + WSO_B1);
  u16*   H0   = (u16*)  (ws + WSO_H0);
  u16*   H1   = (u16*)  (ws + WSO_H1);
  u16*   X    = (u16*)  (ws + WSO_X);
  float* hseq = (float*)(ws + WSO_HSEQ);
  unsigned* bar = (unsigned*)(ws + WSO_BAR);
  float* out = (float*)d_out;

  k_packF0<<<2560, 256, 0, stream>>>(Wx0, Wh0, W0F);
  k_packF1<<<640, 256, 0, stream>>>(Wx1, Wh1, W1F);
  k_bias<<<16, 256, 0, stream>>>(bx0, bh0, bx1, bh1, b0, b1);
  k_init<<<2048, 256, 0, stream>>>(H0, H1, bar);
  k_init2<<<256, 256, 0, stream>>>(x, X);

  MP p;
  p.x = x; p.W0F = W0F; p.W1F = W1F; p.b0 = b0; p.b1 = b1;
  p.H0 = H0; p.H1 = H1; p.X = X; p.hseq = hseq; p.out = out; p.bar = bar;
  void* kargs[] = { (void*)&p };
  hipLaunchCooperativeKernel((const void*)k_main, dim3(NB), dim3(NT), kargs, 0, stream);

  k_final<<<256, 256, 0, stream>>>(hseq, Wout, bout, out);
}

// Round 9
// 1744.094 us; speedup vs baseline: 1.0375x; 1.0375x over previous
//
#include <hip/hip_runtime.h>
#include <hip/hip_bf16.h>

typedef unsigned short u16;
typedef unsigned int u32;
typedef unsigned long long u64;
typedef __attribute__((ext_vector_type(8))) short short8;
typedef __attribute__((ext_vector_type(4))) float f32x4;

#define NB 256
#define NT 512          // 8 waves
#define TS 128
#define LDK 136         // 128 + 8 bf16 pad

// d_out offsets (floats): [out][h_n0][h_n1][c_n0][c_n1]
#define OFF_H0  786432
#define OFF_H1  1048576
#define OFF_C0  1114112
#define OFF_C1  1376256

// ws offsets (bytes) — common region
#define WSO_W0F  0                         // 10,485,760
#define WSO_W1F  (WSO_W0F + 10485760)      // 2,621,440
#define WSO_B0   (WSO_W1F + 2621440)       // 16,384
#define WSO_B1   (WSO_B0  + 16384)         // 4,096
#define WSO_X    (WSO_B1  + 4096)          // 262,144 (2 panels)
#define WSO_BAR  (WSO_X   + 262144)
#define BAR_DW   (4096 + 64)               // flags 256x16dw + rel 4x16dw
#define WSO_VAR  (WSO_BAR + BAR_DW*4)
// OLD path: H0 panels (1,048,576) | H1 panels (262,144) | hseq f32 (33,554,432)
#define NEED_OLD (WSO_VAR + 1048576 + 262144 + 33554432)
// SEQ path: H0seq 129x524,288 | H1seq 129x131,072
#define H0SEQ_BYTES (129*524288)
#define H1SEQ_BYTES (129*131072)
#define NEED_SEQ (WSO_VAR + H0SEQ_BYTES + H1SEQ_BYTES)

struct MP {
  const float* x;
  const u16*  W0F;
  const u16*  W1F;
  const float* b0;      // [4096] n=h*4+g
  const float* b1;      // [1024]
  u16*  H0;             // SEQ: H0seq base (129 panels of 262144 u16); OLD: 2 parity panels
  u16*  H1;             // SEQ: H1seq base (129 panels of 65536 u16);  OLD: 2 parity panels
  u16*  X;              // 2 x [256][256] bf16 panels (sc1)
  float* hseqF;         // OLD only: [128][256][256] f32
  float* out;
  unsigned* bar;
};

__device__ __forceinline__ float sigm(float x){ return 1.f/(1.f+__expf(-x)); }
__device__ __forceinline__ float tanh_(float x){
  float t = __expf(-2.f*fabsf(x));
  float r = (1.f - t)/(1.f + t);
  return x < 0.f ? -r : r;
}
__device__ __forceinline__ u16 f2b(float v){
  __hip_bfloat16 h = __float2bfloat16(v);
  return *reinterpret_cast<u16*>(&h);
}
__device__ __forceinline__ float b2f(u16 u){
  u32 w = ((u32)u) << 16;
  return *reinterpret_cast<float*>(&w);
}
__device__ __forceinline__ void ast32(u16* p, u32 v){
  __hip_atomic_store((u32*)p, v, __ATOMIC_RELAXED, __HIP_MEMORY_SCOPE_AGENT);
}
__device__ __forceinline__ f32x4 MF(short8 a, short8 b, f32x4 c){
  return __builtin_amdgcn_mfma_f32_16x16x32_bf16(a, b, c, 0, 0, 0);
}

#define STRX(x) #x
#define PLOADO(dst, ptr, off) asm volatile("global_load_dwordx4 %0, %1, off offset:" STRX(off) : "=v"(dst) : "v"(ptr))
#define CLOADO(dst, ptr, off) asm volatile("global_load_dwordx4 %0, %1, off offset:" STRX(off) " sc0 sc1" : "=v"(dst) : "v"(ptr))
__device__ __forceinline__ void cwait(){
  asm volatile("s_waitcnt vmcnt(0)" ::: "memory");
  __builtin_amdgcn_sched_barrier(0);
}

#define ISS_A2C(PTR, R0,R1) do{ const u16* _s=(PTR); CLOADO(R0,_s,0); CLOADO(R1,_s,16); }while(0)
#define ISS_A2P(PTR, R0,R1) do{ const u16* _s=(PTR); PLOADO(R0,_s,0); PLOADO(R1,_s,16); }while(0)
#define ST_A2(R0,R1) do{ u16* _d = As + ar*LDK + s0*8; \
    *(short8*)&_d[0]=R0; *(short8*)&_d[8]=R1; }while(0)
#define ISS_B8(PTR, R0,R1,R2,R3,R4,R5,R6,R7) do{ const u16* _s=(PTR); const u16* _s2=_s+2048; \
    PLOADO(R0,_s,0); PLOADO(R1,_s,1024); PLOADO(R2,_s,2048); PLOADO(R3,_s,3072); \
    PLOADO(R4,_s2,0); PLOADO(R5,_s2,1024); PLOADO(R6,_s2,2048); PLOADO(R7,_s2,3072); }while(0)
#define ISS_B4(PTR, R0,R1,R2,R3) do{ const u16* _s=(PTR); \
    PLOADO(R0,_s,0); PLOADO(R1,_s,1024); PLOADO(R2,_s,2048); PLOADO(R3,_s,3072); }while(0)

// ---------------- prologue kernels ----------------

__global__ void k_packF0(const float* __restrict__ Wx, const float* __restrict__ Wh,
                         u16* __restrict__ W0F){
  int gid = blockIdx.x*256 + threadIdx.x;       // 655360
  int F = gid >> 6, lane = gid & 63;
  int kk = F & 3, nf = (F >> 2) & 1;
  int r1 = F >> 3, wn = r1 & 3;
  int r2 = r1 >> 2, kt = r2 % 10, nt = r2 / 10;
  int n = nt*128 + wn*32 + nf*16 + (lane & 15);
  int h = n >> 2, g = n & 3;
  int kb = kt*128 + kk*32 + (lane >> 4)*8;
  union { u16 u[8]; short8 v; } pk;
#pragma unroll
  for (int j = 0; j < 8; ++j) {
    int k = kb + j;
    float v = (k < 256) ? Wx[((size_t)g*256 + k)*1024 + h]
                        : Wh[((size_t)g*1024 + (k-256))*1024 + h];
    pk.u[j] = f2b(v);
  }
  *(short8*)&W0F[(size_t)F*512 + lane*8] = pk.v;
}

__global__ void k_packF1(const float* __restrict__ Wx, const float* __restrict__ Wh,
                         u16* __restrict__ W1F){
  int gid = blockIdx.x*256 + threadIdx.x;       // 163840
  int F = gid >> 6, lane = gid & 63;
  int kk = F & 3;
  int r1 = F >> 2, wn = r1 & 3;
  int r2 = r1 >> 2, kt = r2 % 10, ntp = r2 / 10;
  int n = ntp*64 + wn*16 + (lane & 15);
  int h = n >> 2, g = n & 3;
  int kb = kt*128 + kk*32 + (lane >> 4)*8;
  union { u16 u[8]; short8 v; } pk;
#pragma unroll
  for (int j = 0; j < 8; ++j) {
    int k = kb + j;
    float v = (k < 1024) ? Wx[((size_t)g*1024 + k)*256 + h]
                         : Wh[((size_t)g*256 + (k-1024))*256 + h];
    pk.u[j] = f2b(v);
  }
  *(short8*)&W1F[(size_t)F*512 + lane*8] = pk.v;
}

__global__ void k_bias(const float* __restrict__ bx0, const float* __restrict__ bh0,
                       const float* __restrict__ bx1, const float* __restrict__ bh1,
                       float* __restrict__ b0, float* __restrict__ b1){
  int n = blockIdx.x*256 + threadIdx.x;
  if (n < 4096) { int h = n >> 2, g = n & 3; b0[n] = bx0[g*1024 + h] + bh0[g*1024 + h]; }
  if (n < 1024) { int h = n >> 2, g = n & 3; b1[n] = bx1[g*256 + h] + bh1[g*256 + h]; }
}

__global__ void k_init(u16* __restrict__ H0, u16* __restrict__ H1,
                       unsigned* __restrict__ bar, int nH0, int nH1){
  int i = blockIdx.x*256 + threadIdx.x;         // 2048 blocks -> 524288
  if (i < nH0) H0[i] = 0;
  if (i < nH1) H1[i] = 0;
  if (i < BAR_DW) bar[i] = 0u;
}

__global__ void k_init2(const float* __restrict__ x, u16* __restrict__ X0){
  int i = blockIdx.x*256 + threadIdx.x;         // 65536
  X0[i] = f2b(x[(size_t)(i >> 8)*32768 + (i & 255)]);
}

// ------------- store/poll group barrier (R8, unchanged) --------------------
__device__ __forceinline__ void gbar_worker(unsigned* flags, unsigned* rel,
                                            int bid, unsigned gen){
  __syncthreads();
  if (threadIdx.x == 0) {
    __hip_atomic_store(&flags[bid*16], gen, __ATOMIC_RELAXED, __HIP_MEMORY_SCOPE_AGENT);
    while (__hip_atomic_load(rel, __ATOMIC_RELAXED, __HIP_MEMORY_SCOPE_AGENT) < gen)
      __builtin_amdgcn_s_sleep(1);
  }
  __syncthreads();
}
__device__ __forceinline__ void gbar_agg(unsigned* flags, unsigned* rel,
                                         int grp, unsigned gen){
  __syncthreads();
  int tid = threadIdx.x;
  if (tid < 64) {
    int tb;
    if (tid < 32)      tb = grp*32 + tid;
    else if (tid < 48) tb = 128 + grp*16 + (tid - 32);
    else if (tid < 63) tb = 193 + grp*16 + (tid - 48);
    else               tb = -1;
    unsigned v = gen;
    for (;;) {
      if (tb >= 0)
        v = __hip_atomic_load(&flags[tb*16], __ATOMIC_RELAXED, __HIP_MEMORY_SCOPE_AGENT);
      if (__all((int)(v >= gen))) break;
      __builtin_amdgcn_s_sleep(1);
    }
    if (tid == 0)
      __hip_atomic_store(rel, gen, __ATOMIC_RELAXED, __HIP_MEMORY_SCOPE_AGENT);
  }
  __syncthreads();
}

// ---------------- phase0: blocks 0..127, tile 64m x 128n, 8 waves 2x4 ------
template<int SEQ>
__device__ void phase0(const MP& p, int t, char* smem, float* c0){
  const int bid = blockIdx.x, tid = threadIdx.x;
  const int xcd = bid & 7, local = (bid >> 3) & 3, grp = bid >> 5;
  const int nt = xcd*4 + local;
  const int m0 = grp*64, n0 = nt*128;
  const int lane = tid & 63, wid = tid >> 6;
  const int wm = wid >> 2, wn = wid & 3;
  const int lrow = lane & 15, kgrp = lane >> 4;
  u16* As = (u16*)smem;                 // [64][LDK]
  const u16* Xp   = p.X + (size_t)(t & 1)*65536;
  const u16* H0rd = SEQ ? p.H0 + (size_t)t*262144        // panel t (plain)
                        : p.H0 + (size_t)(t & 1)*262144; // parity panel (sc1)
  const int ar = tid >> 3, s0 = (tid & 7)*2;
  const u16* bbase = p.W0F + (size_t)(nt*40 + wn)*4096 + lane*8;

  auto aptr = [&](int kt)->const u16* {
    return (kt < 2) ? Xp   + (size_t)(m0+ar)*256  + kt*128     + s0*8
                    : H0rd + (size_t)(m0+ar)*1024 + (kt-2)*128 + s0*8;
  };
  auto bptr = [&](int kt)->const u16* { return bbase + (size_t)kt*16384; };

  short8 raa0, raa1, rab0, rab1;
  short8 rba0, rba1, rba2, rba3, rba4, rba5, rba6, rba7;
  short8 rbb0, rbb1, rbb2, rbb3, rbb4, rbb5, rbb6, rbb7;
  f32x4 acc00 = {0,0,0,0}, acc01 = {0,0,0,0}, acc10 = {0,0,0,0}, acc11 = {0,0,0,0};

  auto issA = [&](int kt, short8& r0, short8& r1){
    const u16* s = aptr(kt);
    if (SEQ && kt >= 2) { ISS_A2P(s, r0, r1); } else { ISS_A2C(s, r0, r1); }
  };

#define MFMA_P0(B0,B1,B2,B3,B4,B5,B6,B7) do{ short8 a0, a1; \
    a0 = *(const short8*)&As[(wm*32      + lrow)*LDK +  0 + kgrp*8]; \
    a1 = *(const short8*)&As[(wm*32 + 16 + lrow)*LDK +  0 + kgrp*8]; \
    acc00 = MF(a0,B0,acc00); acc01 = MF(a0,B4,acc01); acc10 = MF(a1,B0,acc10); acc11 = MF(a1,B4,acc11); \
    a0 = *(const short8*)&As[(wm*32      + lrow)*LDK + 32 + kgrp*8]; \
    a1 = *(const short8*)&As[(wm*32 + 16 + lrow)*LDK + 32 + kgrp*8]; \
    acc00 = MF(a0,B1,acc00); acc01 = MF(a0,B5,acc01); acc10 = MF(a1,B1,acc10); acc11 = MF(a1,B5,acc11); \
    a0 = *(const short8*)&As[(wm*32      + lrow)*LDK + 64 + kgrp*8]; \
    a1 = *(const short8*)&As[(wm*32 + 16 + lrow)*LDK + 64 + kgrp*8]; \
    acc00 = MF(a0,B2,acc00); acc01 = MF(a0,B6,acc01); acc10 = MF(a1,B2,acc10); acc11 = MF(a1,B6,acc11); \
    a0 = *(const short8*)&As[(wm*32      + lrow)*LDK + 96 + kgrp*8]; \
    a1 = *(const short8*)&As[(wm*32 + 16 + lrow)*LDK + 96 + kgrp*8]; \
    acc00 = MF(a0,B3,acc00); acc01 = MF(a0,B7,acc01); acc10 = MF(a1,B3,acc10); acc11 = MF(a1,B7,acc11); }while(0)

  issA(0, raa0,raa1);
  ISS_B8(bptr(0), rba0,rba1,rba2,rba3,rba4,rba5,rba6,rba7);
  for (int k2 = 0; k2 < 5; ++k2) {
    const int kto = 2*k2 + 1;
    cwait();
    __syncthreads();
    ST_A2(raa0,raa1);
    __syncthreads();
    issA(kto, rab0,rab1);
    ISS_B8(bptr(kto), rbb0,rbb1,rbb2,rbb3,rbb4,rbb5,rbb6,rbb7);
    MFMA_P0(rba0,rba1,rba2,rba3,rba4,rba5,rba6,rba7);
    cwait();
    __syncthreads();
    ST_A2(rab0,rab1);
    __syncthreads();
    if (kto < 9) {
      issA(kto+1, raa0,raa1);
      ISS_B8(bptr(kto+1), rba0,rba1,rba2,rba3,rba4,rba5,rba6,rba7);
    }
    MFMA_P0(rbb0,rbb1,rbb2,rbb3,rbb4,rbb5,rbb6,rbb7);
  }
  __syncthreads();

  float* gl = (float*)smem;  // [64][132]
#pragma unroll
  for (int r = 0; r < 4; ++r) {
    gl[(wm*32      + kgrp*4 + r)*132 + wn*32      + lrow] = acc00[r];
    gl[(wm*32      + kgrp*4 + r)*132 + wn*32 + 16 + lrow] = acc01[r];
    gl[(wm*32 + 16 + kgrp*4 + r)*132 + wn*32      + lrow] = acc10[r];
    gl[(wm*32 + 16 + kgrp*4 + r)*132 + wn*32 + 16 + lrow] = acc11[r];
  }
  __syncthreads();
  u16* H0wr = SEQ ? p.H0 + (size_t)(t+1)*262144
                  : p.H0 + (size_t)((t+1) & 1)*262144;
#pragma unroll
  for (int rep = 0; rep < 2; ++rep) {
    int e = tid + rep*NT;
    int bl = e >> 4, hp = e & 15;
    int b = m0 + bl, h = nt*32 + hp*2;
    float hn[2];
#pragma unroll
    for (int q = 0; q < 2; ++q) {
      int col = (hp*2 + q)*4;
      float gi = gl[bl*132 + col+0] + p.b0[n0 + col+0];
      float gf = gl[bl*132 + col+1] + p.b0[n0 + col+1];
      float go = gl[bl*132 + col+2] + p.b0[n0 + col+2];
      float gc = gl[bl*132 + col+3] + p.b0[n0 + col+3];
      float cn = sigm(gf)*c0[rep*2+q] + sigm(gi)*tanh_(gc);
      hn[q] = sigm(go)*tanh_(cn);
      c0[rep*2+q] = cn;
      if (t == TS-1) {
        p.out[OFF_H0 + (size_t)b*1024 + h + q] = hn[q];
        p.out[OFF_C0 + (size_t)b*1024 + h + q] = cn;
      }
    }
    ast32(H0wr + (size_t)b*1024 + h, (u32)f2b(hn[0]) | ((u32)f2b(hn[1]) << 16));
  }
}

// ---------------- phase1: blocks 128..191, tile 64m x 64n, 8 waves 2x4 -----
template<int SEQ>
__device__ void phase1(const MP& p, int t, char* smem, float* c1){
  const int tid = threadIdx.x;
  const int j = blockIdx.x - 128;
  const int xcd = j & 7, local = (j >> 3) & 1, grp = j >> 4;
  const int ntp = xcd*2 + local;
  const int m0 = grp*64, n0 = ntp*64;
  const int lane = tid & 63, wid = tid >> 6;
  const int wm = wid >> 2, wn = wid & 3;
  const int lrow = lane & 15, kgrp = lane >> 4;
  u16* As = (u16*)smem;                 // [64][LDK]
  const u16* H0r = SEQ ? p.H0 + (size_t)(t+1)*262144         // h0(t), plain
                       : p.H0 + (size_t)((t+1) & 1)*262144;  // sc1
  const u16* H1r = SEQ ? p.H1 + (size_t)t*65536              // h1(t-1), plain
                       : p.H1 + (size_t)(t & 1)*65536;       // sc1
  const int ar = tid >> 3, s0 = (tid & 7)*2;
  const u16* bbase = p.W1F + (size_t)(ntp*40 + wn)*2048 + lane*8;

  auto aptr = [&](int kt)->const u16* {
    return (kt < 8) ? H0r + (size_t)(m0+ar)*1024 + kt*128     + s0*8
                    : H1r + (size_t)(m0+ar)*256  + (kt-8)*128 + s0*8;
  };
  auto bptr = [&](int kt)->const u16* { return bbase + (size_t)kt*8192; };

  auto issA = [&](int kt, short8& r0, short8& r1){
    const u16* s = aptr(kt);
    if (SEQ) { ISS_A2P(s, r0, r1); } else { ISS_A2C(s, r0, r1); }
  };

  short8 raa0, raa1, rab0, rab1;
  short8 rba0, rba1, rba2, rba3, rbb0, rbb1, rbb2, rbb3;
  f32x4 acc0 = {0,0,0,0}, acc1 = {0,0,0,0};

#define MFMA_P1(B0,B1,B2,B3) do{ short8 a0, a1; \
    a0 = *(const short8*)&As[(wm*32      + lrow)*LDK +  0 + kgrp*8]; \
    a1 = *(const short8*)&As[(wm*32 + 16 + lrow)*LDK +  0 + kgrp*8]; \
    acc0 = MF(a0,B0,acc0); acc1 = MF(a1,B0,acc1); \
    a0 = *(const short8*)&As[(wm*32      + lrow)*LDK + 32 + kgrp*8]; \
    a1 = *(const short8*)&As[(wm*32 + 16 + lrow)*LDK + 32 + kgrp*8]; \
    acc0 = MF(a0,B1,acc0); acc1 = MF(a1,B1,acc1); \
    a0 = *(const short8*)&As[(wm*32      + lrow)*LDK + 64 + kgrp*8]; \
    a1 = *(const short8*)&As[(wm*32 + 16 + lrow)*LDK + 64 + kgrp*8]; \
    acc0 = MF(a0,B2,acc0); acc1 = MF(a1,B2,acc1); \
    a0 = *(const short8*)&As[(wm*32      + lrow)*LDK + 96 + kgrp*8]; \
    a1 = *(const short8*)&As[(wm*32 + 16 + lrow)*LDK + 96 + kgrp*8]; \
    acc0 = MF(a0,B3,acc0); acc1 = MF(a1,B3,acc1); }while(0)

  issA(0, raa0,raa1);
  ISS_B4(bptr(0), rba0,rba1,rba2,rba3);
  for (int k2 = 0; k2 < 5; ++k2) {
    const int kto = 2*k2 + 1;
    cwait();
    __syncthreads();
    ST_A2(raa0,raa1);
    __syncthreads();
    issA(kto, rab0,rab1);
    ISS_B4(bptr(kto), rbb0,rbb1,rbb2,rbb3);
    MFMA_P1(rba0,rba1,rba2,rba3);
    cwait();
    __syncthreads();
    ST_A2(rab0,rab1);
    __syncthreads();
    if (kto < 9) {
      issA(kto+1, raa0,raa1);
      ISS_B4(bptr(kto+1), rba0,rba1,rba2,rba3);
    }
    MFMA_P1(rbb0,rbb1,rbb2,rbb3);
  }
  __syncthreads();

  float* gl = (float*)smem;             // [64][68]
#pragma unroll
  for (int r = 0; r < 4; ++r) {
    gl[(wm*32      + kgrp*4 + r)*68 + wn*16 + lrow] = acc0[r];
    gl[(wm*32 + 16 + kgrp*4 + r)*68 + wn*16 + lrow] = acc1[r];
  }
  __syncthreads();
  u16* H1w = SEQ ? p.H1 + (size_t)(t+1)*65536
                 : p.H1 + (size_t)((t+1) & 1)*65536;
  {
    int bl = tid >> 3, hp = tid & 7;
    int b = m0 + bl, h = ntp*16 + hp*2;
    float hn[2];
#pragma unroll
    for (int q = 0; q < 2; ++q) {
      int col = (hp*2 + q)*4;
      float gi = gl[bl*68 + col+0] + p.b1[n0 + col+0];
      float gf = gl[bl*68 + col+1] + p.b1[n0 + col+1];
      float go = gl[bl*68 + col+2] + p.b1[n0 + col+2];
      float gc = gl[bl*68 + col+3] + p.b1[n0 + col+3];
      float cn = sigm(gf)*c1[q] + sigm(gi)*tanh_(gc);
      hn[q] = sigm(go)*tanh_(cn);
      c1[q] = cn;
      if (t == TS-1) {
        p.out[OFF_H1 + (size_t)b*256 + h + q] = hn[q];
        p.out[OFF_C1 + (size_t)b*256 + h + q] = cn;
      }
    }
    ast32(H1w + (size_t)b*256 + h, (u32)f2b(hn[0]) | ((u32)f2b(hn[1]) << 16));
    if (!SEQ)
      *(float2*)&p.hseqF[((size_t)t*256 + b)*256 + h] = make_float2(hn[0], hn[1]);
  }
}

// ---------------- stage blocks 192..255: pre-stage x_{tn} ------------------
__device__ void stage_x(const MP& p, int tn){
  int j = blockIdx.x - 192;
  int mt = j >> 4, j2 = j & 15;
  u16* Xn = p.X + (size_t)(tn & 1)*65536;
  int idx = j2*NT + threadIdx.x;
  int bl = idx >> 7, fp = idx & 127;
  int b = mt*64 + bl;
  const float* xs = &p.x[(size_t)b*32768 + (size_t)tn*256 + fp*2];
  ast32(&Xn[b*256 + fp*2], (u32)f2b(xs[0]) | ((u32)f2b(xs[1]) << 16));
}

template<int SEQ>
__global__ __launch_bounds__(NT) void k_main(MP p){
  __shared__ __attribute__((aligned(16))) char smem[34816];
  float c0[4] = {0.f, 0.f, 0.f, 0.f};
  float c1[2] = {0.f, 0.f};
  const int bid = blockIdx.x;
  const int grp = (bid < 128) ? (bid >> 5)
                : (bid < 192) ? ((bid - 128) >> 4)
                              : ((bid - 192) >> 4);
  unsigned* flags = p.bar;
  unsigned* rel   = p.bar + 4096 + grp*16;
  const bool agg = (bid >= 192) && (((bid - 192) & 15) == 0);
  for (int s = 0; s < TS; ++s) {
    if (bid < 128)        phase0<SEQ>(p, s, smem, c0);
    else if (bid < 192) { if (s >= 1) phase1<SEQ>(p, s-1, smem, c1); }
    else                { if (s+1 < TS) stage_x(p, s+1); }
    if (agg) gbar_agg(flags, rel, grp, (unsigned)(s + 1));
    else     gbar_worker(flags, rel, bid, (unsigned)(s + 1));
  }
  if (bid >= 128 && bid < 192) phase1<SEQ>(p, TS-1, smem, c1);
}

// ---------------- final projection ----------------
__global__ void k_final_old(const float* __restrict__ hseq, const float* __restrict__ Wout,
                            const float* __restrict__ bout, float* __restrict__ out){
  __shared__ float Ws[1536];
  __shared__ float bs[12];
  for (int i = threadIdx.x; i < 1536; i += 256) Ws[i] = Wout[i];
  if (threadIdx.x < 12) bs[threadIdx.x] = bout[threadIdx.x];
  __syncthreads();
  int gid = blockIdx.x*256 + threadIdx.x;
  int b = gid >> 8, ii = gid & 255;
  const float* src = hseq + ((size_t)(ii >> 1)*256 + b)*256 + (ii & 1)*128;
  float acc[12];
#pragma unroll
  for (int k = 0; k < 12; ++k) acc[k] = bs[k];
  for (int jj = 0; jj < 128; jj += 4) {
    float4 v = *(const float4*)&src[jj];
#pragma unroll
    for (int k = 0; k < 12; ++k)
      acc[k] += v.x*Ws[(jj+0)*12+k] + v.y*Ws[(jj+1)*12+k] + v.z*Ws[(jj+2)*12+k] + v.w*Ws[(jj+3)*12+k];
  }
  float* dst = out + (size_t)b*3072 + ii*12;
#pragma unroll
  for (int k = 0; k < 12; ++k) dst[k] = acc[k];
}

__global__ void k_final_seq(const u16* __restrict__ H1seq, const float* __restrict__ Wout,
                            const float* __restrict__ bout, float* __restrict__ out){
  __shared__ float Ws[1536];
  __shared__ float bs[12];
  for (int i = threadIdx.x; i < 1536; i += 256) Ws[i] = Wout[i];
  if (threadIdx.x < 12) bs[threadIdx.x] = bout[threadIdx.x];
  __syncthreads();
  int gid = blockIdx.x*256 + threadIdx.x;
  int b = gid >> 8, ii = gid & 255;
  // hseq[t][b][h] == H1seq panel (t+1): t = ii>>1, h base = (ii&1)*128
  const u16* src = H1seq + (size_t)((ii >> 1) + 1)*65536 + b*256 + (ii & 1)*128;
  float acc[12];
#pragma unroll
  for (int k = 0; k < 12; ++k) acc[k] = bs[k];
  for (int jj = 0; jj < 128; jj += 8) {
    union { u16 u[8]; short8 v; } pk;
    pk.v = *(const short8*)&src[jj];
#pragma unroll
    for (int e = 0; e < 8; ++e) {
      float f = b2f(pk.u[e]);
#pragma unroll
      for (int k = 0; k < 12; ++k) acc[k] += f*Ws[(jj+e)*12+k];
    }
  }
  float* dst = out + (size_t)b*3072 + ii*12;
#pragma unroll
  for (int k = 0; k < 12; ++k) dst[k] = acc[k];
}

extern "C" void kernel_launch(void* const* d_in, const int* in_sizes, int n_in,
                              void* d_out, int out_size, void* d_ws, size_t ws_size,
                              hipStream_t stream) {
  const float* x    = (const float*)d_in[0];
  const float* Wx0  = (const float*)d_in[1];
  const float* bx0  = (const float*)d_in[2];
  const float* Wh0  = (const float*)d_in[3];
  const float* bh0  = (const float*)d_in[4];
  const float* Wx1  = (const float*)d_in[5];
  const float* bx1  = (const float*)d_in[6];
  const float* Wh1  = (const float*)d_in[7];
  const float* bh1  = (const float*)d_in[8];
  const float* Wout = (const float*)d_in[9];
  const float* bout = (const float*)d_in[10];

  const bool seq = (ws_size >= (size_t)NEED_SEQ);
  if (!seq && ws_size < (size_t)NEED_OLD) return;

  char* ws = (char*)d_ws;
  u16*   W0F  = (u16*)  (ws + WSO_W0F);
  u16*   W1F  = (u16*)  (ws + WSO_W1F);
  float* b0   = (float*)(ws + WSO_B0);
  float* b1   = (float*)(ws + WSO_B1);
  u16*   X    = (u16*)  (ws + WSO_X);
  unsigned* bar = (unsigned*)(ws + WSO_BAR);
  u16*   H0   = (u16*)  (ws + WSO_VAR);
  u16*   H1   = seq ? (u16*)(ws + WSO_VAR + H0SEQ_BYTES)
                    : (u16*)(ws + WSO_VAR + 1048576);
  float* hseqF = (float*)(ws + WSO_VAR + 1048576 + 262144);  // old path only
  float* out = (float*)d_out;

  k_packF0<<<2560, 256, 0, stream>>>(Wx0, Wh0, W0F);
  k_packF1<<<640, 256, 0, stream>>>(Wx1, Wh1, W1F);
  k_bias<<<16, 256, 0, stream>>>(bx0, bh0, bx1, bh1, b0, b1);
  k_init<<<2048, 256, 0, stream>>>(H0, H1, bar,
                                   seq ? 262144 : 524288,
                                   seq ? 65536  : 131072);
  k_init2<<<256, 256, 0, stream>>>(x, X);

  MP p;
  p.x = x; p.W0F = W0F; p.W1F = W1F; p.b0 = b0; p.b1 = b1;
  p.H0 = H0; p.H1 = H1; p.X = X; p.hseqF = hseqF; p.out = out; p.bar = bar;
  void* kargs[] = { (void*)&p };
  if (seq)
    hipLaunchCooperativeKernel((const void*)k_main<1>, dim3(NB), dim3(NT), kargs, 0, stream);
  else
    hipLaunchCooperativeKernel((const void*)k_main<0>, dim3(NB), dim3(NT), kargs, 0, stream);

  if (seq) k_final_seq<<<256, 256, 0, stream>>>(H1, Wout, bout, out);
  else     k_final_old<<<256, 256, 0, stream>>>(hseqF, Wout, bout, out);
}

// Round 10
// 1568.536 us; speedup vs baseline: 1.1536x; 1.1119x over previous
//
#include <hip/hip_runtime.h>
#include <hip/hip_bf16.h>

typedef unsigned short u16;
typedef unsigned int u32;
typedef unsigned long long u64;
typedef __attribute__((ext_vector_type(8))) short short8;
typedef __attribute__((ext_vector_type(4))) float f32x4;

#define NB 256
#define NT 512          // 8 waves
#define TS 128

// d_out offsets (floats): [out][h_n0][h_n1][c_n0][c_n1]
#define OFF_H0  786432
#define OFF_H1  1048576
#define OFF_C0  1114112
#define OFF_C1  1376256

// ws offsets (bytes)
#define WSO_W0F  0                         // 10,485,760
#define WSO_W1F  (WSO_W0F + 10485760)      // 2,621,440
#define WSO_B0   (WSO_W1F + 2621440)       // 16,384
#define WSO_B1   (WSO_B0  + 16384)         // 4,096
#define WSO_X    (WSO_B1  + 4096)          // 262,144 (2 parity panels)
#define WSO_BAR  (WSO_X   + 262144)
#define BAR_DW   (4096 + 64)               // flags 256x16dw + rel 4x16dw
#define WSO_VAR  (WSO_BAR + BAR_DW*4)
#define H0SEQ_BYTES (129*524288)           // 129 panels x [256][1024] bf16
#define H1SEQ_BYTES (129*131072)           // 129 panels x [256][256]  bf16
#define NEED_SEQ (WSO_VAR + H0SEQ_BYTES + H1SEQ_BYTES)

struct MP {
  const float* x;
  const u16*  W0F;      // layer0 weights, MFMA-fragment layout
  const u16*  W1F;      // layer1 weights, MFMA-fragment layout
  const float* b0;      // [4096] n=h*4+g
  const float* b1;      // [1024]
  u16*  H0;             // H0seq: 129 panels of 262144 u16 (write-once)
  u16*  H1;             // H1seq: 129 panels of 65536 u16  (write-once)
  u16*  X;              // 2 parity panels [256][256] (sc1)
  float* out;
  unsigned* bar;
};

__device__ __forceinline__ float sigm(float x){ return 1.f/(1.f+__expf(-x)); }
__device__ __forceinline__ float tanh_(float x){
  float t = __expf(-2.f*fabsf(x));
  float r = (1.f - t)/(1.f + t);
  return x < 0.f ? -r : r;
}
__device__ __forceinline__ u16 f2b(float v){
  __hip_bfloat16 h = __float2bfloat16(v);
  return *reinterpret_cast<u16*>(&h);
}
__device__ __forceinline__ float b2f(u16 u){
  u32 w = ((u32)u) << 16;
  return *reinterpret_cast<float*>(&w);
}
__device__ __forceinline__ void ast32(u16* p, u32 v){
  __hip_atomic_store((u32*)p, v, __ATOMIC_RELAXED, __HIP_MEMORY_SCOPE_AGENT);
}
__device__ __forceinline__ f32x4 MF(short8 a, short8 b, f32x4 c){
  return __builtin_amdgcn_mfma_f32_16x16x32_bf16(a, b, c, 0, 0, 0);
}
// async global -> LDS, 16B/lane (dest = wave-uniform base + lane*16; src per-lane)
__device__ __forceinline__ void gll16(const void* g, void* l){
  __builtin_amdgcn_global_load_lds(
      (const __attribute__((address_space(1))) void*)g,
      (__attribute__((address_space(3))) void*)l, 16, 0, 0);
}

#define STRX(x) #x
#define PLOADO(dst, ptr, off) asm volatile("global_load_dwordx4 %0, %1, off offset:" STRX(off) : "=v"(dst) : "v"(ptr))
#define CLOADO(dst, ptr, off) asm volatile("global_load_dwordx4 %0, %1, off offset:" STRX(off) " sc0 sc1" : "=v"(dst) : "v"(ptr))
#define VMW(N)  do{ asm volatile("s_waitcnt vmcnt(" STRX(N) ")" ::: "memory"); __builtin_amdgcn_sched_barrier(0); }while(0)
#define LGKM0   do{ asm volatile("s_waitcnt lgkmcnt(0)" ::: "memory"); __builtin_amdgcn_sched_barrier(0); }while(0)
#define BAR     do{ __builtin_amdgcn_s_barrier(); __builtin_amdgcn_sched_barrier(0); }while(0)

// ---------------- prologue kernels (unchanged from R9) ----------------

__global__ void k_packF0(const float* __restrict__ Wx, const float* __restrict__ Wh,
                         u16* __restrict__ W0F){
  int gid = blockIdx.x*256 + threadIdx.x;       // 655360
  int F = gid >> 6, lane = gid & 63;
  int kk = F & 3, nf = (F >> 2) & 1;
  int r1 = F >> 3, wn = r1 & 3;
  int r2 = r1 >> 2, kt = r2 % 10, nt = r2 / 10;
  int n = nt*128 + wn*32 + nf*16 + (lane & 15);
  int h = n >> 2, g = n & 3;
  int kb = kt*128 + kk*32 + (lane >> 4)*8;
  union { u16 u[8]; short8 v; } pk;
#pragma unroll
  for (int j = 0; j < 8; ++j) {
    int k = kb + j;
    float v = (k < 256) ? Wx[((size_t)g*256 + k)*1024 + h]
                        : Wh[((size_t)g*1024 + (k-256))*1024 + h];
    pk.u[j] = f2b(v);
  }
  *(short8*)&W0F[(size_t)F*512 + lane*8] = pk.v;
}

__global__ void k_packF1(const float* __restrict__ Wx, const float* __restrict__ Wh,
                         u16* __restrict__ W1F){
  int gid = blockIdx.x*256 + threadIdx.x;       // 163840
  int F = gid >> 6, lane = gid & 63;
  int kk = F & 3;
  int r1 = F >> 2, wn = r1 & 3;
  int r2 = r1 >> 2, kt = r2 % 10, ntp = r2 / 10;
  int n = ntp*64 + wn*16 + (lane & 15);
  int h = n >> 2, g = n & 3;
  int kb = kt*128 + kk*32 + (lane >> 4)*8;
  union { u16 u[8]; short8 v; } pk;
#pragma unroll
  for (int j = 0; j < 8; ++j) {
    int k = kb + j;
    float v = (k < 1024) ? Wx[((size_t)g*1024 + k)*256 + h]
                         : Wh[((size_t)g*256 + (k-1024))*256 + h];
    pk.u[j] = f2b(v);
  }
  *(short8*)&W1F[(size_t)F*512 + lane*8] = pk.v;
}

__global__ void k_bias(const float* __restrict__ bx0, const float* __restrict__ bh0,
                       const float* __restrict__ bx1, const float* __restrict__ bh1,
                       float* __restrict__ b0, float* __restrict__ b1){
  int n = blockIdx.x*256 + threadIdx.x;
  if (n < 4096) { int h = n >> 2, g = n & 3; b0[n] = bx0[g*1024 + h] + bh0[g*1024 + h]; }
  if (n < 1024) { int h = n >> 2, g = n & 3; b1[n] = bx1[g*256 + h] + bh1[g*256 + h]; }
}

__global__ void k_init(u16* __restrict__ H0, u16* __restrict__ H1,
                       unsigned* __restrict__ bar){
  int i = blockIdx.x*256 + threadIdx.x;         // 1024 blocks -> 262144
  if (i < 262144) H0[i] = 0;                    // H0seq panel 0
  if (i < 65536)  H1[i] = 0;                    // H1seq panel 0
  if (i < BAR_DW) bar[i] = 0u;
}

__global__ void k_init2(const float* __restrict__ x, u16* __restrict__ X0){
  int i = blockIdx.x*256 + threadIdx.x;         // 65536
  X0[i] = f2b(x[(size_t)(i >> 8)*32768 + (i & 255)]);
}

// ------------- store/poll group barrier (R9, unchanged) --------------------
__device__ __forceinline__ void gbar_worker(unsigned* flags, unsigned* rel,
                                            int bid, unsigned gen){
  __syncthreads();
  if (threadIdx.x == 0) {
    __hip_atomic_store(&flags[bid*16], gen, __ATOMIC_RELAXED, __HIP_MEMORY_SCOPE_AGENT);
    while (__hip_atomic_load(rel, __ATOMIC_RELAXED, __HIP_MEMORY_SCOPE_AGENT) < gen)
      __builtin_amdgcn_s_sleep(1);
  }
  __syncthreads();
}
__device__ __forceinline__ void gbar_agg(unsigned* flags, unsigned* rel,
                                         int grp, unsigned gen){
  __syncthreads();
  int tid = threadIdx.x;
  if (tid < 64) {
    int tb;
    if (tid < 32)      tb = grp*32 + tid;
    else if (tid < 48) tb = 128 + grp*16 + (tid - 32);
    else if (tid < 63) tb = 193 + grp*16 + (tid - 48);
    else               tb = -1;
    unsigned v = gen;
    for (;;) {
      if (tb >= 0)
        v = __hip_atomic_load(&flags[tb*16], __ATOMIC_RELAXED, __HIP_MEMORY_SCOPE_AGENT);
      if (__all((int)(v >= gen))) break;
      __builtin_amdgcn_s_sleep(1);
    }
    if (tid == 0)
      __hip_atomic_store(rel, gen, __ATOMIC_RELAXED, __HIP_MEMORY_SCOPE_AGENT);
  }
  __syncthreads();
}

// ---------------- phase0: blocks 0..127, tile 64m x 128n, 8 waves 2x4 ------
// A-tiles: global_load_lds DMA into 4 x 16KB LDS buffers (linear [64][128]),
// source pre-swizzled per-lane (granule ^= row&7); MFMA ds_reads use same XOR.
// Counted vmcnt: per tile = 2 DMA(or 2 CLOAD for X) + 8 B-PLOADs. FIFO audit:
//  pro: B0(8) X0(2) B1(8) X1(2) st2(2)          [22]
//  k0: VMW(12)->B0,X0 | k1: VMW(12)->B1,X1 | k2..7: VMW(12)->st(kt),B(kt)
//  k8: VMW(10) | k9: VMW(0). Body kt adds B(kt+2)(8) + st(kt+3)(2).
__device__ void phase0(const MP& p, int t, char* smem, float* c0){
  const int bid = blockIdx.x, tid = threadIdx.x;
  const int xcd = bid & 7, local = (bid >> 3) & 3, grp = bid >> 5;
  const int nt = xcd*4 + local;
  const int m0 = grp*64, n0 = nt*128;
  const int lane = tid & 63, wid = tid >> 6;
  const int wm = wid >> 2, wn = wid & 3;
  const int lrow = lane & 15, kgrp = lane >> 4;
  const int r4 = lane >> 4, c16 = lane & 15;
  const int rl0 = wid*8 + r4, rl1 = wid*8 + 4 + r4;   // staged rows (this wave)
  const int sw0 = (c16 ^ r4) << 4;                    // rl0&7 == r4
  const int sw1 = (c16 ^ (4 + r4)) << 4;              // rl1&7 == 4+r4
  const char* Xp = (const char*)(p.X + (size_t)(t & 1)*65536);
  const char* Hp = (const char*)(p.H0 + (size_t)t*262144);
  const char* xr0 = Xp + (m0+rl0)*512 + sw0;
  const char* xr1 = Xp + (m0+rl1)*512 + sw1;
  const char* hr0 = Hp + (m0+rl0)*2048 + sw0;
  const char* hr1 = Hp + (m0+rl1)*2048 + sw1;
  char* dst0 = smem + wid*2048;                       // + buf*16384 (+1024 for j=1)
  const u16* bbase = p.W0F + (size_t)(nt*40 + wn)*4096 + lane*8;
  // MFMA read addressing (swizzled)
  const int abase = (wm*32 + lrow)*256 + ((kgrp ^ (lrow & 3)) << 4);
  const int lb6 = (lrow & 4) << 4;                    // 0 or 64

  short8 bA0,bA1,bA2,bA3,bA4,bA5,bA6,bA7;
  short8 bB0,bB1,bB2,bB3,bB4,bB5,bB6,bB7;
  short8 bC0,bC1,bC2,bC3,bC4,bC5,bC6,bC7;
  short8 rx00, rx01, rx10, rx11;
  f32x4 acc00 = {0,0,0,0}, acc01 = {0,0,0,0}, acc10 = {0,0,0,0}, acc11 = {0,0,0,0};

#define P0_ISSB(KT, R0,R1,R2,R3,R4,R5,R6,R7) do{ \
    const u16* _s = bbase + (size_t)(KT)*16384; const u16* _s2 = _s + 2048; \
    PLOADO(R0,_s,0); PLOADO(R1,_s,1024); PLOADO(R2,_s,2048); PLOADO(R3,_s,3072); \
    PLOADO(R4,_s2,0); PLOADO(R5,_s2,1024); PLOADO(R6,_s2,2048); PLOADO(R7,_s2,3072); }while(0)
#define P0_STG(KT, BUFI) do{ \
    gll16(hr0 + ((KT)-2)*256, dst0 + (BUFI)*16384); \
    gll16(hr1 + ((KT)-2)*256, dst0 + (BUFI)*16384 + 1024); }while(0)
#define P0_MF(BUFI, B0,B1,B2,B3,B4,B5,B6,B7) do{ \
    const char* _bp = smem + (BUFI)*16384; short8 a0, a1; \
    a0 = *(const short8*)(_bp + abase + (0 ^ lb6)); \
    a1 = *(const short8*)(_bp + abase + 4096 + (0 ^ lb6)); \
    acc00 = MF(a0,B0,acc00); acc01 = MF(a0,B4,acc01); acc10 = MF(a1,B0,acc10); acc11 = MF(a1,B4,acc11); \
    a0 = *(const short8*)(_bp + abase + (64 ^ lb6)); \
    a1 = *(const short8*)(_bp + abase + 4096 + (64 ^ lb6)); \
    acc00 = MF(a0,B1,acc00); acc01 = MF(a0,B5,acc01); acc10 = MF(a1,B1,acc10); acc11 = MF(a1,B5,acc11); \
    a0 = *(const short8*)(_bp + abase + (128 ^ lb6)); \
    a1 = *(const short8*)(_bp + abase + 4096 + (128 ^ lb6)); \
    acc00 = MF(a0,B2,acc00); acc01 = MF(a0,B6,acc01); acc10 = MF(a1,B2,acc10); acc11 = MF(a1,B6,acc11); \
    a0 = *(const short8*)(_bp + abase + (192 ^ lb6)); \
    a1 = *(const short8*)(_bp + abase + 4096 + (192 ^ lb6)); \
    acc00 = MF(a0,B3,acc00); acc01 = MF(a0,B7,acc01); acc10 = MF(a1,B3,acc10); acc11 = MF(a1,B7,acc11); }while(0)

  P0_ISSB(0, bA0,bA1,bA2,bA3,bA4,bA5,bA6,bA7);
  CLOADO(rx00, xr0, 0); CLOADO(rx01, xr1, 0);
  P0_ISSB(1, bB0,bB1,bB2,bB3,bB4,bB5,bB6,bB7);
  CLOADO(rx10, xr0, 256); CLOADO(rx11, xr1, 256);
  P0_STG(2, 2);
  // k0 (X tile 0 -> buf0 via ds_write)
  VMW(12);
  *(short8*)(smem + rl0*256 + c16*16) = rx00;
  *(short8*)(smem + rl1*256 + c16*16) = rx01;
  LGKM0; BAR;
  P0_MF(0, bA0,bA1,bA2,bA3,bA4,bA5,bA6,bA7);
  P0_ISSB(2, bC0,bC1,bC2,bC3,bC4,bC5,bC6,bC7); P0_STG(3, 3);
  // k1 (X tile 1 -> buf1)
  VMW(12);
  *(short8*)(smem + 16384 + rl0*256 + c16*16) = rx10;
  *(short8*)(smem + 16384 + rl1*256 + c16*16) = rx11;
  LGKM0; BAR;
  P0_MF(1, bB0,bB1,bB2,bB3,bB4,bB5,bB6,bB7);
  P0_ISSB(3, bA0,bA1,bA2,bA3,bA4,bA5,bA6,bA7); P0_STG(4, 0);
  // k2..k7
  VMW(12); BAR; P0_MF(2, bC0,bC1,bC2,bC3,bC4,bC5,bC6,bC7);
  P0_ISSB(4, bB0,bB1,bB2,bB3,bB4,bB5,bB6,bB7); P0_STG(5, 1);
  VMW(12); BAR; P0_MF(3, bA0,bA1,bA2,bA3,bA4,bA5,bA6,bA7);
  P0_ISSB(5, bC0,bC1,bC2,bC3,bC4,bC5,bC6,bC7); P0_STG(6, 2);
  VMW(12); BAR; P0_MF(0, bB0,bB1,bB2,bB3,bB4,bB5,bB6,bB7);
  P0_ISSB(6, bA0,bA1,bA2,bA3,bA4,bA5,bA6,bA7); P0_STG(7, 3);
  VMW(12); BAR; P0_MF(1, bC0,bC1,bC2,bC3,bC4,bC5,bC6,bC7);
  P0_ISSB(7, bB0,bB1,bB2,bB3,bB4,bB5,bB6,bB7); P0_STG(8, 0);
  VMW(12); BAR; P0_MF(2, bA0,bA1,bA2,bA3,bA4,bA5,bA6,bA7);
  P0_ISSB(8, bC0,bC1,bC2,bC3,bC4,bC5,bC6,bC7); P0_STG(9, 1);
  VMW(12); BAR; P0_MF(3, bB0,bB1,bB2,bB3,bB4,bB5,bB6,bB7);
  P0_ISSB(9, bA0,bA1,bA2,bA3,bA4,bA5,bA6,bA7);
  // k8, k9
  VMW(10); BAR; P0_MF(0, bC0,bC1,bC2,bC3,bC4,bC5,bC6,bC7);
  VMW(0);  BAR; P0_MF(1, bA0,bA1,bA2,bA3,bA4,bA5,bA6,bA7);

  // epilogue (R9, unchanged): acc -> LDS transpose -> fused cell, c0 in VGPRs
  __syncthreads();
  float* gl = (float*)smem;  // [64][132]
#pragma unroll
  for (int r = 0; r < 4; ++r) {
    gl[(wm*32      + kgrp*4 + r)*132 + wn*32      + lrow] = acc00[r];
    gl[(wm*32      + kgrp*4 + r)*132 + wn*32 + 16 + lrow] = acc01[r];
    gl[(wm*32 + 16 + kgrp*4 + r)*132 + wn*32      + lrow] = acc10[r];
    gl[(wm*32 + 16 + kgrp*4 + r)*132 + wn*32 + 16 + lrow] = acc11[r];
  }
  __syncthreads();
  u16* H0wr = p.H0 + (size_t)(t+1)*262144;
#pragma unroll
  for (int rep = 0; rep < 2; ++rep) {
    int e = tid + rep*NT;
    int bl = e >> 4, hp = e & 15;
    int b = m0 + bl, h = nt*32 + hp*2;
    float hn[2];
#pragma unroll
    for (int q = 0; q < 2; ++q) {
      int col = (hp*2 + q)*4;
      float gi = gl[bl*132 + col+0] + p.b0[n0 + col+0];
      float gf = gl[bl*132 + col+1] + p.b0[n0 + col+1];
      float go = gl[bl*132 + col+2] + p.b0[n0 + col+2];
      float gc = gl[bl*132 + col+3] + p.b0[n0 + col+3];
      float cn = sigm(gf)*c0[rep*2+q] + sigm(gi)*tanh_(gc);
      hn[q] = sigm(go)*tanh_(cn);
      c0[rep*2+q] = cn;
      if (t == TS-1) {
        p.out[OFF_H0 + (size_t)b*1024 + h + q] = hn[q];
        p.out[OFF_C0 + (size_t)b*1024 + h + q] = cn;
      }
    }
    ast32(H0wr + (size_t)b*1024 + h, (u32)f2b(hn[0]) | ((u32)f2b(hn[1]) << 16));
  }
}

// ---------------- phase1: blocks 128..191, tile 64m x 64n, 8 waves 2x4 -----
// Per tile: 2 DMA + 4 B-PLOADs. FIFO: pro B0(4) st0(2) B1(4) st1(2) st2(2) [14]
// k0..7: VMW(8); k8: VMW(6); k9: VMW(0). Body kt adds B(kt+2)(4) + st(kt+3)(2).
__device__ void phase1(const MP& p, int t, char* smem, float* c1){
  const int tid = threadIdx.x;
  const int j = blockIdx.x - 128;
  const int xcd = j & 7, local = (j >> 3) & 1, grp = j >> 4;
  const int ntp = xcd*2 + local;
  const int m0 = grp*64, n0 = ntp*64;
  const int lane = tid & 63, wid = tid >> 6;
  const int wm = wid >> 2, wn = wid & 3;
  const int lrow = lane & 15, kgrp = lane >> 4;
  const int r4 = lane >> 4, c16 = lane & 15;
  const int rl0 = wid*8 + r4, rl1 = wid*8 + 4 + r4;
  const int sw0 = (c16 ^ r4) << 4;
  const int sw1 = (c16 ^ (4 + r4)) << 4;
  const char* H0r = (const char*)(p.H0 + (size_t)(t+1)*262144);  // h0(t)
  const char* H1r = (const char*)(p.H1 + (size_t)t*65536);       // h1(t-1)
  const char* h0a = H0r + (m0+rl0)*2048 + sw0;
  const char* h0b = H0r + (m0+rl1)*2048 + sw1;
  const char* h1a = H1r + (m0+rl0)*512 + sw0;
  const char* h1b = H1r + (m0+rl1)*512 + sw1;
  char* dst0 = smem + wid*2048;
  const u16* bbase = p.W1F + (size_t)(ntp*40 + wn)*2048 + lane*8;
  const int abase = (wm*32 + lrow)*256 + ((kgrp ^ (lrow & 3)) << 4);
  const int lb6 = (lrow & 4) << 4;

  short8 bA0,bA1,bA2,bA3, bB0,bB1,bB2,bB3, bC0,bC1,bC2,bC3;
  f32x4 acc0 = {0,0,0,0}, acc1 = {0,0,0,0};

#define P1_ISSB(KT, R0,R1,R2,R3) do{ const u16* _s = bbase + (size_t)(KT)*8192; \
    PLOADO(R0,_s,0); PLOADO(R1,_s,1024); PLOADO(R2,_s,2048); PLOADO(R3,_s,3072); }while(0)
#define P1_STG0(KT, BUFI) do{ \
    gll16(h0a + (KT)*256, dst0 + (BUFI)*16384); \
    gll16(h0b + (KT)*256, dst0 + (BUFI)*16384 + 1024); }while(0)
#define P1_STG1(KT, BUFI) do{ \
    gll16(h1a + ((KT)-8)*256, dst0 + (BUFI)*16384); \
    gll16(h1b + ((KT)-8)*256, dst0 + (BUFI)*16384 + 1024); }while(0)
#define P1_MF(BUFI, B0,B1,B2,B3) do{ \
    const char* _bp = smem + (BUFI)*16384; short8 a0, a1; \
    a0 = *(const short8*)(_bp + abase + (0 ^ lb6)); \
    a1 = *(const short8*)(_bp + abase + 4096 + (0 ^ lb6)); \
    acc0 = MF(a0,B0,acc0); acc1 = MF(a1,B0,acc1); \
    a0 = *(const short8*)(_bp + abase + (64 ^ lb6)); \
    a1 = *(const short8*)(_bp + abase + 4096 + (64 ^ lb6)); \
    acc0 = MF(a0,B1,acc0); acc1 = MF(a1,B1,acc1); \
    a0 = *(const short8*)(_bp + abase + (128 ^ lb6)); \
    a1 = *(const short8*)(_bp + abase + 4096 + (128 ^ lb6)); \
    acc0 = MF(a0,B2,acc0); acc1 = MF(a1,B2,acc1); \
    a0 = *(const short8*)(_bp + abase + (192 ^ lb6)); \
    a1 = *(const short8*)(_bp + abase + 4096 + (192 ^ lb6)); \
    acc0 = MF(a0,B3,acc0); acc1 = MF(a1,B3,acc1); }while(0)

  P1_ISSB(0, bA0,bA1,bA2,bA3); P1_STG0(0, 0);
  P1_ISSB(1, bB0,bB1,bB2,bB3); P1_STG0(1, 1);
  P1_STG0(2, 2);
  VMW(8); BAR; P1_MF(0, bA0,bA1,bA2,bA3); P1_ISSB(2, bC0,bC1,bC2,bC3); P1_STG0(3, 3);
  VMW(8); BAR; P1_MF(1, bB0,bB1,bB2,bB3); P1_ISSB(3, bA0,bA1,bA2,bA3); P1_STG0(4, 0);
  VMW(8); BAR; P1_MF(2, bC0,bC1,bC2,bC3); P1_ISSB(4, bB0,bB1,bB2,bB3); P1_STG0(5, 1);
  VMW(8); BAR; P1_MF(3, bA0,bA1,bA2,bA3); P1_ISSB(5, bC0,bC1,bC2,bC3); P1_STG0(6, 2);
  VMW(8); BAR; P1_MF(0, bB0,bB1,bB2,bB3); P1_ISSB(6, bA0,bA1,bA2,bA3); P1_STG0(7, 3);
  VMW(8); BAR; P1_MF(1, bC0,bC1,bC2,bC3); P1_ISSB(7, bB0,bB1,bB2,bB3); P1_STG1(8, 0);
  VMW(8); BAR; P1_MF(2, bA0,bA1,bA2,bA3); P1_ISSB(8, bC0,bC1,bC2,bC3); P1_STG1(9, 1);
  VMW(8); BAR; P1_MF(3, bB0,bB1,bB2,bB3); P1_ISSB(9, bA0,bA1,bA2,bA3);
  VMW(6); BAR; P1_MF(0, bC0,bC1,bC2,bC3);
  VMW(0); BAR; P1_MF(1, bA0,bA1,bA2,bA3);

  __syncthreads();
  float* gl = (float*)smem;             // [64][68]
#pragma unroll
  for (int r = 0; r < 4; ++r) {
    gl[(wm*32      + kgrp*4 + r)*68 + wn*16 + lrow] = acc0[r];
    gl[(wm*32 + 16 + kgrp*4 + r)*68 + wn*16 + lrow] = acc1[r];
  }
  __syncthreads();
  u16* H1w = p.H1 + (size_t)(t+1)*65536;
  {
    int bl = tid >> 3, hp = tid & 7;
    int b = m0 + bl, h = ntp*16 + hp*2;
    float hn[2];
#pragma unroll
    for (int q = 0; q < 2; ++q) {
      int col = (hp*2 + q)*4;
      float gi = gl[bl*68 + col+0] + p.b1[n0 + col+0];
      float gf = gl[bl*68 + col+1] + p.b1[n0 + col+1];
      float go = gl[bl*68 + col+2] + p.b1[n0 + col+2];
      float gc = gl[bl*68 + col+3] + p.b1[n0 + col+3];
      float cn = sigm(gf)*c1[q] + sigm(gi)*tanh_(gc);
      hn[q] = sigm(go)*tanh_(cn);
      c1[q] = cn;
      if (t == TS-1) {
        p.out[OFF_H1 + (size_t)b*256 + h + q] = hn[q];
        p.out[OFF_C1 + (size_t)b*256 + h + q] = cn;
      }
    }
    ast32(H1w + (size_t)b*256 + h, (u32)f2b(hn[0]) | ((u32)f2b(hn[1]) << 16));
  }
}

// ---------------- stage blocks 192..255: pre-stage x_{tn} (sc1 parity) -----
__device__ void stage_x(const MP& p, int tn){
  int j = blockIdx.x - 192;
  int mt = j >> 4, j2 = j & 15;
  u16* Xn = p.X + (size_t)(tn & 1)*65536;
  int idx = j2*NT + threadIdx.x;
  int bl = idx >> 7, fp = idx & 127;
  int b = mt*64 + bl;
  const float* xs = &p.x[(size_t)b*32768 + (size_t)tn*256 + fp*2];
  ast32(&Xn[b*256 + fp*2], (u32)f2b(xs[0]) | ((u32)f2b(xs[1]) << 16));
}

__global__ __launch_bounds__(NT) void k_main(MP p){
  __shared__ __attribute__((aligned(16))) char smem[65536];   // 4 x 16KB A-buffers
  float c0[4] = {0.f, 0.f, 0.f, 0.f};
  float c1[2] = {0.f, 0.f};
  const int bid = blockIdx.x;
  const int grp = (bid < 128) ? (bid >> 5)
                : (bid < 192) ? ((bid - 128) >> 4)
                              : ((bid - 192) >> 4);
  unsigned* flags = p.bar;
  unsigned* rel   = p.bar + 4096 + grp*16;
  const bool agg = (bid >= 192) && (((bid - 192) & 15) == 0);
  for (int s = 0; s < TS; ++s) {
    if (bid < 128)        phase0(p, s, smem, c0);                  // layer0 @ t=s
    else if (bid < 192) { if (s >= 1) phase1(p, s-1, smem, c1); }  // layer1 @ t=s-1
    else                { if (s+1 < TS) stage_x(p, s+1); }
    if (agg) gbar_agg(flags, rel, grp, (unsigned)(s + 1));
    else     gbar_worker(flags, rel, bid, (unsigned)(s + 1));
  }
  if (bid >= 128 && bid < 192) phase1(p, TS-1, smem, c1);          // pipeline tail
}

// ---------------- final projection (reads H1seq bf16, linear) --------------
__global__ void k_final_seq(const u16* __restrict__ H1seq, const float* __restrict__ Wout,
                            const float* __restrict__ bout, float* __restrict__ out){
  __shared__ float Ws[1536];
  __shared__ float bs[12];
  for (int i = threadIdx.x; i < 1536; i += 256) Ws[i] = Wout[i];
  if (threadIdx.x < 12) bs[threadIdx.x] = bout[threadIdx.x];
  __syncthreads();
  int gid = blockIdx.x*256 + threadIdx.x;
  int b = gid >> 8, ii = gid & 255;
  const u16* src = H1seq + (size_t)((ii >> 1) + 1)*65536 + b*256 + (ii & 1)*128;
  float acc[12];
#pragma unroll
  for (int k = 0; k < 12; ++k) acc[k] = bs[k];
  for (int jj = 0; jj < 128; jj += 8) {
    union { u16 u[8]; short8 v; } pk;
    pk.v = *(const short8*)&src[jj];
#pragma unroll
    for (int e = 0; e < 8; ++e) {
      float f = b2f(pk.u[e]);
#pragma unroll
      for (int k = 0; k < 12; ++k) acc[k] += f*Ws[(jj+e)*12+k];
    }
  }
  float* dst = out + (size_t)b*3072 + ii*12;
#pragma unroll
  for (int k = 0; k < 12; ++k) dst[k] = acc[k];
}

extern "C" void kernel_launch(void* const* d_in, const int* in_sizes, int n_in,
                              void* d_out, int out_size, void* d_ws, size_t ws_size,
                              hipStream_t stream) {
  if (ws_size < (size_t)NEED_SEQ) return;   // fail visibly if ws too small
  const float* x    = (const float*)d_in[0];
  const float* Wx0  = (const float*)d_in[1];
  const float* bx0  = (const float*)d_in[2];
  const float* Wh0  = (const float*)d_in[3];
  const float* bh0  = (const float*)d_in[4];
  const float* Wx1  = (const float*)d_in[5];
  const float* bx1  = (const float*)d_in[6];
  const float* Wh1  = (const float*)d_in[7];
  const float* bh1  = (const float*)d_in[8];
  const float* Wout = (const float*)d_in[9];
  const float* bout = (const float*)d_in[10];

  char* ws = (char*)d_ws;
  u16*   W0F  = (u16*)  (ws + WSO_W0F);
  u16*   W1F  = (u16*)  (ws + WSO_W1F);
  float* b0   = (float*)(ws + WSO_B0);
  float* b1   = (float*)(ws + WSO_B1);
  u16*   X    = (u16*)  (ws + WSO_X);
  unsigned* bar = (unsigned*)(ws + WSO_BAR);
  u16*   H0   = (u16*)  (ws + WSO_VAR);
  u16*   H1   = (u16*)  (ws + WSO_VAR + H0SEQ_BYTES);
  float* out = (float*)d_out;

  k_packF0<<<2560, 256, 0, stream>>>(Wx0, Wh0, W0F);
  k_packF1<<<640, 256, 0, stream>>>(Wx1, Wh1, W1F);
  k_bias<<<16, 256, 0, stream>>>(bx0, bh0, bx1, bh1, b0, b1);
  k_init<<<1024, 256, 0, stream>>>(H0, H1, bar);
  k_init2<<<256, 256, 0, stream>>>(x, X);

  MP p;
  p.x = x; p.W0F = W0F; p.W1F = W1F; p.b0 = b0; p.b1 = b1;
  p.H0 = H0; p.H1 = H1; p.X = X; p.out = out; p.bar = bar;
  void* kargs[] = { (void*)&p };
  hipLaunchCooperativeKernel((const void*)k_main, dim3(NB), dim3(NT), kargs, 0, stream);

  k_final_seq<<<256, 256, 0, stream>>>(H1, Wout, bout, out);
}

// Round 12
// 1487.152 us; speedup vs baseline: 1.2167x; 1.0547x over previous
//
#include <hip/hip_runtime.h>
#include <hip/hip_bf16.h>

typedef unsigned short u16;
typedef unsigned int u32;
typedef unsigned long long u64;
typedef __attribute__((ext_vector_type(8))) short short8;
typedef __attribute__((ext_vector_type(4))) float f32x4;

#define NB 256
#define NT 512          // 8 waves
#define TS 128

// d_out offsets (floats): [out][h_n0][h_n1][c_n0][c_n1]
#define OFF_H0  786432
#define OFF_H1  1048576
#define OFF_C0  1114112
#define OFF_C1  1376256

// ws layout (bytes)
#define WSO_W0F  0                          // 10,485,760
#define WSO_W1F  (WSO_W0F + 10485760)       // 2,621,440
#define WSO_B0   (WSO_W1F + 2621440)        // 16,384
#define WSO_B1   (WSO_B0  + 16384)          // 4,096
#define WSO_BAR  (WSO_B1  + 4096)
#define BAR_DW   (4096 + 64)                // flags 256x16dw + rel 4x16dw
#define WSO_H0   (WSO_BAR + BAR_DW*4)
#define H0SEQ_BYTES (129*524288)            // 129 panels [256][1024] bf16
#define WSO_H1   (WSO_H0 + H0SEQ_BYTES)
#define H1SEQ_BYTES (129*131072)            // 129 panels [256][256] bf16
#define WS_NEED  (WSO_H1 + H1SEQ_BYTES)     // ~97.7 MB

// LDS map (bytes): bufs 4x16K | Xbuf 2x16K | B1 pin 40K
#define LDS_XB   65536
#define LDS_B1   98304
#define LDS_SZ   139264

struct MP {
  const float* x;
  const u16*  W0F;      // frag(nt,kt,wn,kk): u16 off = nt*81920 + kt*8192 + wn*2048 + kk*512
  const u16*  W1F;      // frag(ntp,kt,kk): byte off = ntp*40960 + (kt*4+kk)*1024
  const float* b0;      // [4096] n = h*4+g
  const float* b1;      // [1024]
  u16*  H0;             // H0seq: 129 x [256][1024]
  u16*  H1;             // H1seq: 129 x [256][256] (== hseq, bf16)
  float* out;
  unsigned* bar;
};

__device__ __forceinline__ float sigm(float x){ return 1.f/(1.f+__expf(-x)); }
__device__ __forceinline__ float tanh_(float x){
  float t = __expf(-2.f*fabsf(x));
  float r = (1.f - t)/(1.f + t);
  return x < 0.f ? -r : r;
}
__device__ __forceinline__ u16 f2b(float v){
  __hip_bfloat16 h = __float2bfloat16(v);
  return *reinterpret_cast<u16*>(&h);
}
__device__ __forceinline__ float b2f(u16 u){
  u32 w = ((u32)u) << 16;
  return *reinterpret_cast<float*>(&w);
}
__device__ __forceinline__ void ast32(u16* p, u32 v){
  __hip_atomic_store((u32*)p, v, __ATOMIC_RELAXED, __HIP_MEMORY_SCOPE_AGENT);
}
__device__ __forceinline__ f32x4 MF(short8 a, short8 b, f32x4 c){
  return __builtin_amdgcn_mfma_f32_16x16x32_bf16(a, b, c, 0, 0, 0);
}
__device__ __forceinline__ void gll16(const void* g, void* l){
  __builtin_amdgcn_global_load_lds(
      (const __attribute__((address_space(1))) void*)g,
      (__attribute__((address_space(3))) void*)l, 16, 0, 0);
}

#define STRX(x) #x
#define PLOADO(dst, ptr, off) asm volatile("global_load_dwordx4 %0, %1, off offset:" STRX(off) : "=v"(dst) : "v"(ptr))
#define VMW(N)  do{ asm volatile("s_waitcnt vmcnt(" STRX(N) ")" ::: "memory"); __builtin_amdgcn_sched_barrier(0); }while(0)
#define BAR     do{ __builtin_amdgcn_s_barrier(); __builtin_amdgcn_sched_barrier(0); }while(0)

// ---------------- prologue kernels ----------------

// W0F: F = ((nt*10+kt)*4+wn)*4+kk; n = nt*64 + wn*16 + (lane&15); k = kt*128 + kk*32 + (lane>>4)*8
__global__ void k_packF0(const float* __restrict__ Wx, const float* __restrict__ Wh,
                         u16* __restrict__ W0F){
  int gid = blockIdx.x*256 + threadIdx.x;       // 655360
  int F = gid >> 6, lane = gid & 63;
  int kk = F & 3, wn = (F >> 2) & 3;
  int r = F >> 4, kt = r % 10, nt = r / 10;     // nt 0..63
  int n = nt*64 + wn*16 + (lane & 15);
  int h = n >> 2, g = n & 3;
  int kb = kt*128 + kk*32 + (lane >> 4)*8;
  union { u16 u[8]; short8 v; } pk;
#pragma unroll
  for (int j = 0; j < 8; ++j) {
    int k = kb + j;
    float v = (k < 256) ? Wx[((size_t)g*256 + k)*1024 + h]
                        : Wh[((size_t)g*1024 + (k-256))*1024 + h];
    pk.u[j] = f2b(v);
  }
  *(short8*)&W0F[(size_t)F*512 + lane*8] = pk.v;
}

// W1F: F = ntp*40 + kt*4 + kk; n = ntp*16 + (lane&15)
__global__ void k_packF1(const float* __restrict__ Wx, const float* __restrict__ Wh,
                         u16* __restrict__ W1F){
  int gid = blockIdx.x*256 + threadIdx.x;       // 163840
  int F = gid >> 6, lane = gid & 63;
  int kk = F & 3, kt = (F >> 2) % 10, ntp = F / 40;  // ntp 0..63
  int n = ntp*16 + (lane & 15);
  int h = n >> 2, g = n & 3;
  int kb = kt*128 + kk*32 + (lane >> 4)*8;
  union { u16 u[8]; short8 v; } pk;
#pragma unroll
  for (int j = 0; j < 8; ++j) {
    int k = kb + j;
    float v = (k < 1024) ? Wx[((size_t)g*1024 + k)*256 + h]
                         : Wh[((size_t)g*256 + (k-1024))*256 + h];
    pk.u[j] = f2b(v);
  }
  *(short8*)&W1F[(size_t)F*512 + lane*8] = pk.v;
}

__global__ void k_bias(const float* __restrict__ bx0, const float* __restrict__ bh0,
                       const float* __restrict__ bx1, const float* __restrict__ bh1,
                       float* __restrict__ b0, float* __restrict__ b1){
  int n = blockIdx.x*256 + threadIdx.x;
  if (n < 4096) { int h = n >> 2, g = n & 3; b0[n] = bx0[g*1024 + h] + bh0[g*1024 + h]; }
  if (n < 1024) { int h = n >> 2, g = n & 3; b1[n] = bx1[g*256 + h] + bh1[g*256 + h]; }
}

__global__ void k_init(u16* __restrict__ H0, u16* __restrict__ H1,
                       unsigned* __restrict__ bar){
  int i = blockIdx.x*256 + threadIdx.x;         // 1024 blocks -> 262144
  if (i < 262144) H0[i] = 0;                    // panel 0
  if (i < 65536)  H1[i] = 0;                    // panel 0
  if (i < BAR_DW) bar[i] = 0u;
}

// ---------------- device helpers ----------------

// x[t=g] fp32 -> bf16 into X-bufs (block-local), swizzled like DMA tiles
__device__ __forceinline__ void xcvt(const MP& p, int g, char* smem){
  const int tid = threadIdx.x;
  const int row = tid >> 3, f0 = (tid & 7) << 5;
  const int m0 = (blockIdx.x >> 6) << 6;
  const float* xs = p.x + (size_t)(m0 + row)*32768 + (size_t)g*256 + f0;
  f32x4 v0,v1,v2,v3,v4,v5,v6,v7;
  PLOADO(v0, xs, 0);  PLOADO(v1, xs, 16); PLOADO(v2, xs, 32); PLOADO(v3, xs, 48);
  PLOADO(v4, xs, 64); PLOADO(v5, xs, 80); PLOADO(v6, xs, 96); PLOADO(v7, xs, 112);
  VMW(0);
  char* xb = smem + LDS_XB + ((f0 >> 7) << 14);
  const int cb = (f0 & 127) >> 3, sw = row & 7;
  union { u16 u[8]; short8 s; } pk;
#define XPK(VA, VB, CC) \
  pk.u[0]=f2b(VA[0]); pk.u[1]=f2b(VA[1]); pk.u[2]=f2b(VA[2]); pk.u[3]=f2b(VA[3]); \
  pk.u[4]=f2b(VB[0]); pk.u[5]=f2b(VB[1]); pk.u[6]=f2b(VB[2]); pk.u[7]=f2b(VB[3]); \
  *(short8*)(xb + row*256 + ((((cb+(CC)) ^ sw))<<4)) = pk.s;
  XPK(v0,v1,0) XPK(v2,v3,1) XPK(v4,v5,2) XPK(v6,v7,3)
#undef XPK
}

// ---------- phase0: layer0, tile 64m x 64n, 10 K-tiles (2 X + 8 H0) ----------
__device__ void phase0(const MP& p, int g, char* smem, float* c0){
  const int bid = blockIdx.x, tid = threadIdx.x;
  const int grp = bid >> 6, nt = bid & 63;
  const int m0 = grp*64, n0 = nt*64;
  const int lane = tid & 63, wid = tid >> 6;
  const int wm = wid >> 2, wn = wid & 3;
  const int lrow = lane & 15, kgrp = lane >> 4;
  const int sw = lrow & 7;
  const int r8 = lane >> 4, c16 = lane & 15;
  const int row0 = wid*8 + r8, row1 = wid*8 + 4 + r8;
  const char* Hp = (const char*)(p.H0 + (size_t)g*262144);
  const char* h0 = Hp + (size_t)(m0+row0)*2048 + ((c16 ^ (row0 & 7))<<4);
  const char* h1 = Hp + (size_t)(m0+row1)*2048 + ((c16 ^ (row1 & 7))<<4);
  char* d0 = smem + wid*2048;
  char* d1 = smem + wid*2048 + 1024;
  // FIX(R11->R12): u16 strides — nt*81920, wn*2048 (was byte values halved)
  const u16* bb = p.W0F + (size_t)nt*81920 + wn*2048 + lane*8;

  short8 bA0,bA1,bA2,bA3, bB0,bB1,bB2,bB3, bC0,bC1,bC2,bC3;
  f32x4 acc0 = {0,0,0,0}, acc1 = {0,0,0,0};

#define P0_B(KT, R0,R1,R2,R3) do{ const u16* _s = bb + (size_t)(KT)*8192; \
    PLOADO(R0,_s,0); PLOADO(R1,_s,1024); PLOADO(R2,_s,2048); PLOADO(R3,_s,3072); }while(0)
#define P0_S(KT) do{ const int _o = ((KT)-2)*256, _bi = (((KT)-2)&3)*16384; \
    gll16(h0 + _o, d0 + _bi); gll16(h1 + _o, d1 + _bi); }while(0)
#define P0_MFB(BP, B0_,B1_,B2_,B3_) do{ const char* _bp = (BP); short8 _a0,_a1; \
    const int _r0 = (wm*32 + lrow)*256, _r1 = _r0 + 16*256; \
    _a0 = *(const short8*)(_bp + _r0 + (((0+kgrp) ^ sw)<<4)); \
    _a1 = *(const short8*)(_bp + _r1 + (((0+kgrp) ^ sw)<<4)); \
    acc0 = MF(_a0,B0_,acc0); acc1 = MF(_a1,B0_,acc1); \
    _a0 = *(const short8*)(_bp + _r0 + (((4+kgrp) ^ sw)<<4)); \
    _a1 = *(const short8*)(_bp + _r1 + (((4+kgrp) ^ sw)<<4)); \
    acc0 = MF(_a0,B1_,acc0); acc1 = MF(_a1,B1_,acc1); \
    _a0 = *(const short8*)(_bp + _r0 + (((8+kgrp) ^ sw)<<4)); \
    _a1 = *(const short8*)(_bp + _r1 + (((8+kgrp) ^ sw)<<4)); \
    acc0 = MF(_a0,B2_,acc0); acc1 = MF(_a1,B2_,acc1); \
    _a0 = *(const short8*)(_bp + _r0 + (((12+kgrp) ^ sw)<<4)); \
    _a1 = *(const short8*)(_bp + _r1 + (((12+kgrp) ^ sw)<<4)); \
    acc0 = MF(_a0,B3_,acc0); acc1 = MF(_a1,B3_,acc1); }while(0)

  // FIFO audit (ops): pro [B0(4) B1(4) B2(4) S2..S5(2 each)] = 20
  P0_B(0, bA0,bA1,bA2,bA3); P0_B(1, bB0,bB1,bB2,bB3); P0_B(2, bC0,bC1,bC2,bC3);
  P0_S(2); P0_S(3); P0_S(4); P0_S(5);
  VMW(16); BAR; P0_MFB(smem + LDS_XB,         bA0,bA1,bA2,bA3); P0_B(3, bA0,bA1,bA2,bA3);
  VMW(16); BAR; P0_MFB(smem + LDS_XB + 16384, bB0,bB1,bB2,bB3); P0_B(4, bB0,bB1,bB2,bB3);
  VMW(14); BAR; P0_MFB(smem,         bC0,bC1,bC2,bC3); P0_B(5, bC0,bC1,bC2,bC3); P0_S(6);
  VMW(10); BAR; P0_MFB(smem + 16384, bA0,bA1,bA2,bA3); P0_B(6, bA0,bA1,bA2,bA3); P0_S(7);
  VMW(12); BAR; P0_MFB(smem + 32768, bB0,bB1,bB2,bB3); P0_B(7, bB0,bB1,bB2,bB3); P0_S(8);
  VMW(14); BAR; P0_MFB(smem + 49152, bC0,bC1,bC2,bC3); P0_B(8, bC0,bC1,bC2,bC3); P0_S(9);
  VMW(14); BAR; P0_MFB(smem,         bA0,bA1,bA2,bA3); P0_B(9, bA0,bA1,bA2,bA3);
  VMW(12); BAR; P0_MFB(smem + 16384, bB0,bB1,bB2,bB3);
  VMW(6);  BAR; P0_MFB(smem + 32768, bC0,bC1,bC2,bC3);
  VMW(0);  BAR; P0_MFB(smem + 49152, bA0,bA1,bA2,bA3);

  // epilogue: acc -> LDS [64][68] -> fused cell (c0 in VGPRs, 1 h-pair/thread)
  __syncthreads();
  float* gl = (float*)smem;
#pragma unroll
  for (int r = 0; r < 4; ++r) {
    gl[(wm*32      + kgrp*4 + r)*68 + wn*16 + lrow] = acc0[r];
    gl[(wm*32 + 16 + kgrp*4 + r)*68 + wn*16 + lrow] = acc1[r];
  }
  __syncthreads();
  u16* H0w = p.H0 + (size_t)(g+1)*262144;
  {
    int bl = tid >> 3, hp = tid & 7;
    int b = m0 + bl, h = nt*16 + hp*2;
    float hn[2];
#pragma unroll
    for (int q = 0; q < 2; ++q) {
      int col = (hp*2 + q)*4;
      float gi = gl[bl*68 + col+0] + p.b0[n0 + col+0];
      float gf = gl[bl*68 + col+1] + p.b0[n0 + col+1];
      float go = gl[bl*68 + col+2] + p.b0[n0 + col+2];
      float gc = gl[bl*68 + col+3] + p.b0[n0 + col+3];
      float cn = sigm(gf)*c0[q] + sigm(gi)*tanh_(gc);
      hn[q] = sigm(go)*tanh_(cn);
      c0[q] = cn;
      if (g == TS-1) {
        p.out[OFF_H0 + (size_t)b*1024 + h + q] = hn[q];
        p.out[OFF_C0 + (size_t)b*1024 + h + q] = cn;
      }
    }
    ast32(H0w + (size_t)b*1024 + h, (u32)f2b(hn[0]) | ((u32)f2b(hn[1]) << 16));
  }
}

// ---------- phase1: layer1, tile 64m x 16n, B1 pinned in LDS ----------
__device__ void phase1(const MP& p, int g, char* smem, float* c1){
  const int bid = blockIdx.x, tid = threadIdx.x;
  const int grp = bid >> 6, ntp = bid & 63;
  const int m0 = grp*64, n1 = ntp*16;
  const int lane = tid & 63, wid = tid >> 6;
  const int lrow = lane & 15, kgrp = lane >> 4;
  const int sw = lrow & 7;
  const int r8 = lane >> 4, c16 = lane & 15;
  const int row0 = wid*8 + r8, row1 = wid*8 + 4 + r8;
  const char* HA = (const char*)(p.H0 + (size_t)g*262144);
  const char* HB = (const char*)(p.H1 + (size_t)(g-1)*65536);
  const char* hA0 = HA + (size_t)(m0+row0)*2048 + ((c16 ^ (row0 & 7))<<4);
  const char* hA1 = HA + (size_t)(m0+row1)*2048 + ((c16 ^ (row1 & 7))<<4);
  const char* hB0 = HB + (size_t)(m0+row0)*512  + ((c16 ^ (row0 & 7))<<4);
  const char* hB1 = HB + (size_t)(m0+row1)*512  + ((c16 ^ (row1 & 7))<<4);
  char* d0 = smem + wid*2048;
  char* d1 = smem + wid*2048 + 1024;
  const char* b1p = smem + LDS_B1;
  f32x4 acc = {0,0,0,0};

#define P1_D(KT) do{ const int _bi = ((KT)&3)*16384; \
    if ((KT) < 8) { gll16(hA0 + (KT)*256, d0 + _bi); gll16(hA1 + (KT)*256, d1 + _bi); } \
    else          { gll16(hB0 + ((KT)-8)*256, d0 + _bi); gll16(hB1 + ((KT)-8)*256, d1 + _bi); } }while(0)
#define P1_MF(BUFI, KT) do{ const char* _bp = smem + (BUFI)*16384; \
    const int _ro = (wid*16 + lrow)*256; short8 _a, _b; \
    _a = *(const short8*)(_bp + _ro + (((0+kgrp) ^ sw)<<4)); \
    _b = *(const short8*)(b1p + (((KT)*4+0)<<10) + lane*16); acc = MF(_a,_b,acc); \
    _a = *(const short8*)(_bp + _ro + (((4+kgrp) ^ sw)<<4)); \
    _b = *(const short8*)(b1p + (((KT)*4+1)<<10) + lane*16); acc = MF(_a,_b,acc); \
    _a = *(const short8*)(_bp + _ro + (((8+kgrp) ^ sw)<<4)); \
    _b = *(const short8*)(b1p + (((KT)*4+2)<<10) + lane*16); acc = MF(_a,_b,acc); \
    _a = *(const short8*)(_bp + _ro + (((12+kgrp) ^ sw)<<4)); \
    _b = *(const short8*)(b1p + (((KT)*4+3)<<10) + lane*16); acc = MF(_a,_b,acc); }while(0)

  // FIFO (2 ops per D): pro D0,D1,D2; body k issues D(k+3) (k<=6)
  P1_D(0); P1_D(1); P1_D(2);
  VMW(4); BAR; if (wid < 4) P1_MF(0, 0); P1_D(3);
  VMW(4); BAR; if (wid < 4) P1_MF(1, 1); P1_D(4);
  VMW(4); BAR; if (wid < 4) P1_MF(2, 2); P1_D(5);
  VMW(4); BAR; if (wid < 4) P1_MF(3, 3); P1_D(6);
  VMW(4); BAR; if (wid < 4) P1_MF(0, 4); P1_D(7);
  VMW(4); BAR; if (wid < 4) P1_MF(1, 5); P1_D(8);
  VMW(4); BAR; if (wid < 4) P1_MF(2, 6); P1_D(9);
  VMW(4); BAR; if (wid < 4) P1_MF(3, 7);
  VMW(2); BAR; if (wid < 4) P1_MF(0, 8);
  VMW(0); BAR; if (wid < 4) P1_MF(1, 9);

  __syncthreads();
  float* gl = (float*)smem;             // [64][20]
  if (wid < 4) {
#pragma unroll
    for (int r = 0; r < 4; ++r)
      gl[(wid*16 + kgrp*4 + r)*20 + lrow] = acc[r];
  }
  __syncthreads();
  u16* H1w = p.H1 + (size_t)g*65536;
  if (tid < 128) {
    int bl = tid >> 1, hp = tid & 1;
    int b = m0 + bl, h = ntp*4 + hp*2;
    float hn[2];
#pragma unroll
    for (int q = 0; q < 2; ++q) {
      int col = (hp*2 + q)*4;
      float gi = gl[bl*20 + col+0] + p.b1[n1 + col+0];
      float gf = gl[bl*20 + col+1] + p.b1[n1 + col+1];
      float go = gl[bl*20 + col+2] + p.b1[n1 + col+2];
      float gc = gl[bl*20 + col+3] + p.b1[n1 + col+3];
      float cn = sigm(gf)*c1[q] + sigm(gi)*tanh_(gc);
      hn[q] = sigm(go)*tanh_(cn);
      c1[q] = cn;
      if (g == TS) {
        p.out[OFF_H1 + (size_t)b*256 + h + q] = hn[q];
        p.out[OFF_C1 + (size_t)b*256 + h + q] = cn;
      }
    }
    ast32(H1w + (size_t)b*256 + h, (u32)f2b(hn[0]) | ((u32)f2b(hn[1]) << 16));
  }
}

// ---------------- main cooperative kernel ----------------
__global__ __launch_bounds__(NT) void k_main(MP p){
  __shared__ __attribute__((aligned(16))) char smem[LDS_SZ];
  float c0[2] = {0.f, 0.f};
  float c1[2] = {0.f, 0.f};
  const int bid = blockIdx.x, tid = threadIdx.x;
  const int grp = bid >> 6, j = bid & 63;
  unsigned* flags = p.bar;
  unsigned* rel   = p.bar + 4096 + grp*16;

  // pin B1 slice in LDS (40 KB) — once
  {
    int wid = tid >> 6, lane = tid & 63;
    const char* wsrc = (const char*)p.W1F + (size_t)j*40960 + lane*16;
#pragma unroll
    for (int q = 0; q < 5; ++q) {
      int f = wid*5 + q;
      gll16(wsrc + f*1024, smem + LDS_B1 + f*1024);
    }
    VMW(0);
  }
  xcvt(p, 0, smem);
  __syncthreads();
  phase0(p, 0, smem, c0);               // panel 0 -> 1

  for (int g = 1; g <= TS; ++g) {
    // arrive (drains h0/h1 sc1 stores), then shadow-convert x[g], then wait
    __syncthreads();
    if (j == 0) {
      if (tid >= 1 && tid < 64) {
        while (__hip_atomic_load(&flags[(grp*64 + tid)*16], __ATOMIC_RELAXED,
                                 __HIP_MEMORY_SCOPE_AGENT) < (unsigned)g)
          __builtin_amdgcn_s_sleep(1);
      }
      __syncthreads();
      if (tid == 0)
        __hip_atomic_store(rel, (unsigned)g, __ATOMIC_RELAXED, __HIP_MEMORY_SCOPE_AGENT);
    } else {
      if (tid == 0)
        __hip_atomic_store(&flags[bid*16], (unsigned)g, __ATOMIC_RELAXED,
                           __HIP_MEMORY_SCOPE_AGENT);
    }
    if (g < TS) xcvt(p, g, smem);       // block-local, overlaps propagation
    if (j != 0 && tid == 0) {
      while (__hip_atomic_load(rel, __ATOMIC_RELAXED, __HIP_MEMORY_SCOPE_AGENT) < (unsigned)g)
        __builtin_amdgcn_s_sleep(1);
    }
    __syncthreads();
    phase1(p, g, smem, c1);             // h0 panel g + h1 panel g-1 -> h1 panel g
    __syncthreads();
    if (g < TS) phase0(p, g, smem, c0); // h0 panel g + x[g] -> panel g+1
  }
}

// ---------------- final projection (reads H1seq bf16) ----------------
__global__ void k_final_seq(const u16* __restrict__ H1seq, const float* __restrict__ Wout,
                            const float* __restrict__ bout, float* __restrict__ out){
  __shared__ float Ws[1536];
  __shared__ float bs[12];
  for (int i = threadIdx.x; i < 1536; i += 256) Ws[i] = Wout[i];
  if (threadIdx.x < 12) bs[threadIdx.x] = bout[threadIdx.x];
  __syncthreads();
  int gid = blockIdx.x*256 + threadIdx.x;
  int b = gid >> 8, ii = gid & 255;
  const u16* src = H1seq + (size_t)((ii >> 1) + 1)*65536 + b*256 + (ii & 1)*128;
  float acc[12];
#pragma unroll
  for (int k = 0; k < 12; ++k) acc[k] = bs[k];
  for (int jj = 0; jj < 128; jj += 8) {
    union { u16 u[8]; short8 v; } pk;
    pk.v = *(const short8*)&src[jj];
#pragma unroll
    for (int e = 0; e < 8; ++e) {
      float f = b2f(pk.u[e]);
#pragma unroll
      for (int k = 0; k < 12; ++k) acc[k] += f*Ws[(jj+e)*12+k];
    }
  }
  float* dst = out + (size_t)b*3072 + ii*12;
#pragma unroll
  for (int k = 0; k < 12; ++k) dst[k] = acc[k];
}

extern "C" void kernel_launch(void* const* d_in, const int* in_sizes, int n_in,
                              void* d_out, int out_size, void* d_ws, size_t ws_size,
                              hipStream_t stream) {
  if (ws_size < (size_t)WS_NEED) return;   // fail visibly if ws too small
  const float* x    = (const float*)d_in[0];
  const float* Wx0  = (const float*)d_in[1];
  const float* bx0  = (const float*)d_in[2];
  const float* Wh0  = (const float*)d_in[3];
  const float* bh0  = (const float*)d_in[4];
  const float* Wx1  = (const float*)d_in[5];
  const float* bx1  = (const float*)d_in[6];
  const float* Wh1  = (const float*)d_in[7];
  const float* bh1  = (const float*)d_in[8];
  const float* Wout = (const float*)d_in[9];
  const float* bout = (const float*)d_in[10];

  char* ws = (char*)d_ws;
  u16*   W0F  = (u16*)  (ws + WSO_W0F);
  u16*   W1F  = (u16*)  (ws + WSO_W1F);
  float* b0   = (float*)(ws + WSO_B0);
  float* b1   = (float*)(ws + WSO_B1);
  unsigned* bar = (unsigned*)(ws + WSO_BAR);
  u16*   H0   = (u16*)  (ws + WSO_H0);
  u16*   H1   = (u16*)  (ws + WSO_H1);
  float* out = (float*)d_out;

  k_packF0<<<2560, 256, 0, stream>>>(Wx0, Wh0, W0F);
  k_packF1<<<640, 256, 0, stream>>>(Wx1, Wh1, W1F);
  k_bias<<<16, 256, 0, stream>>>(bx0, bh0, bx1, bh1, b0, b1);
  k_init<<<1024, 256, 0, stream>>>(H0, H1, bar);

  MP p;
  p.x = x; p.W0F = W0F; p.W1F = W1F; p.b0 = b0; p.b1 = b1;
  p.H0 = H0; p.H1 = H1; p.out = out; p.bar = bar;
  void* kargs[] = { (void*)&p };
  hipLaunchCooperativeKernel((const void*)k_main, dim3(NB), dim3(NT), kargs, 0, stream);

  k_final_seq<<<256, 256, 0, stream>>>(H1, Wout, bout, out);
}

// Round 13
// 1204.792 us; speedup vs baseline: 1.5019x; 1.2344x over previous
//
#include <hip/hip_runtime.h>
#include <hip/hip_bf16.h>

typedef unsigned short u16;
typedef unsigned int u32;
typedef unsigned long long u64;
typedef __attribute__((ext_vector_type(8))) short short8;
typedef __attribute__((ext_vector_type(4))) float f32x4;

#define NB 256
#define NT 512          // 8 waves
#define TS 128

// d_out offsets (floats): [out][h_n0][h_n1][c_n0][c_n1]
#define OFF_H0  786432
#define OFF_H1  1048576
#define OFF_C0  1114112
#define OFF_C1  1376256

// ws layout (bytes)
#define WSO_W0F  0                          // 10,485,760
#define WSO_W1F  (WSO_W0F + 10485760)       // 2,621,440
#define WSO_B0   (WSO_W1F + 2621440)        // 16,384
#define WSO_B1   (WSO_B0  + 16384)          // 4,096
#define WSO_BAR  (WSO_B1  + 4096)
#define BAR_DW   (4096 + 64)                // flags 256x16dw + rel 4x16dw
#define WSO_H0   (WSO_BAR + BAR_DW*4)
#define H0SEQ_BYTES (129*524288)            // 129 panels [256][1024] bf16
#define WSO_H1   (WSO_H0 + H0SEQ_BYTES)
#define H1SEQ_BYTES (129*131072)            // 129 panels [256][256] bf16
#define WS_NEED  (WSO_H1 + H1SEQ_BYTES)     // ~97.7 MB

// LDS map (bytes): bufs 4x16K | Xbuf 2x16K | B1 pin 40K
#define LDS_XB   65536
#define LDS_B1   98304
#define LDS_SZ   139264

struct MP {
  const float* x;
  const u16*  W0F;      // frag(nt,kt,wn,kk): u16 off = nt*81920 + kt*8192 + wn*2048 + kk*512
  const u16*  W1F;      // frag(ntp,kt,kk): byte off = ntp*40960 + (kt*4+kk)*1024
  const float* b0;      // [4096] n = h*4+g
  const float* b1;      // [1024]
  u16*  H0;             // H0seq: 129 x [256][1024]
  u16*  H1;             // H1seq: 129 x [256][256] (== hseq, bf16)
  float* out;
  unsigned* bar;
};

__device__ __forceinline__ float sigm(float x){ return 1.f/(1.f+__expf(-x)); }
__device__ __forceinline__ float tanh_(float x){
  float t = __expf(-2.f*fabsf(x));
  float r = (1.f - t)/(1.f + t);
  return x < 0.f ? -r : r;
}
__device__ __forceinline__ u16 f2b(float v){
  __hip_bfloat16 h = __float2bfloat16(v);
  return *reinterpret_cast<u16*>(&h);
}
__device__ __forceinline__ float b2f(u16 u){
  u32 w = ((u32)u) << 16;
  return *reinterpret_cast<float*>(&w);
}
__device__ __forceinline__ void ast32(u16* p, u32 v){
  __hip_atomic_store((u32*)p, v, __ATOMIC_RELAXED, __HIP_MEMORY_SCOPE_AGENT);
}
__device__ __forceinline__ f32x4 MF(short8 a, short8 b, f32x4 c){
  return __builtin_amdgcn_mfma_f32_16x16x32_bf16(a, b, c, 0, 0, 0);
}
__device__ __forceinline__ void gll16(const void* g, void* l){
  __builtin_amdgcn_global_load_lds(
      (const __attribute__((address_space(1))) void*)g,
      (__attribute__((address_space(3))) void*)l, 16, 0, 0);
}

#define STRX(x) #x
#define PLOADO(dst, ptr, off) asm volatile("global_load_dwordx4 %0, %1, off offset:" STRX(off) : "=v"(dst) : "v"(ptr))
#define VMW(N)  do{ asm volatile("s_waitcnt vmcnt(" STRX(N) ")" ::: "memory"); __builtin_amdgcn_sched_barrier(0); }while(0)
#define BAR     do{ __builtin_amdgcn_s_barrier(); __builtin_amdgcn_sched_barrier(0); }while(0)

// ---------------- prologue kernels (R12, unchanged) ----------------

__global__ void k_packF0(const float* __restrict__ Wx, const float* __restrict__ Wh,
                         u16* __restrict__ W0F){
  int gid = blockIdx.x*256 + threadIdx.x;       // 655360
  int F = gid >> 6, lane = gid & 63;
  int kk = F & 3, wn = (F >> 2) & 3;
  int r = F >> 4, kt = r % 10, nt = r / 10;     // nt 0..63
  int n = nt*64 + wn*16 + (lane & 15);
  int h = n >> 2, g = n & 3;
  int kb = kt*128 + kk*32 + (lane >> 4)*8;
  union { u16 u[8]; short8 v; } pk;
#pragma unroll
  for (int j = 0; j < 8; ++j) {
    int k = kb + j;
    float v = (k < 256) ? Wx[((size_t)g*256 + k)*1024 + h]
                        : Wh[((size_t)g*1024 + (k-256))*1024 + h];
    pk.u[j] = f2b(v);
  }
  *(short8*)&W0F[(size_t)F*512 + lane*8] = pk.v;
}

__global__ void k_packF1(const float* __restrict__ Wx, const float* __restrict__ Wh,
                         u16* __restrict__ W1F){
  int gid = blockIdx.x*256 + threadIdx.x;       // 163840
  int F = gid >> 6, lane = gid & 63;
  int kk = F & 3, kt = (F >> 2) % 10, ntp = F / 40;  // ntp 0..63
  int n = ntp*16 + (lane & 15);
  int h = n >> 2, g = n & 3;
  int kb = kt*128 + kk*32 + (lane >> 4)*8;
  union { u16 u[8]; short8 v; } pk;
#pragma unroll
  for (int j = 0; j < 8; ++j) {
    int k = kb + j;
    float v = (k < 1024) ? Wx[((size_t)g*1024 + k)*256 + h]
                         : Wh[((size_t)g*256 + (k-1024))*256 + h];
    pk.u[j] = f2b(v);
  }
  *(short8*)&W1F[(size_t)F*512 + lane*8] = pk.v;
}

__global__ void k_bias(const float* __restrict__ bx0, const float* __restrict__ bh0,
                       const float* __restrict__ bx1, const float* __restrict__ bh1,
                       float* __restrict__ b0, float* __restrict__ b1){
  int n = blockIdx.x*256 + threadIdx.x;
  if (n < 4096) { int h = n >> 2, g = n & 3; b0[n] = bx0[g*1024 + h] + bh0[g*1024 + h]; }
  if (n < 1024) { int h = n >> 2, g = n & 3; b1[n] = bx1[g*256 + h] + bh1[g*256 + h]; }
}

__global__ void k_init(u16* __restrict__ H0, u16* __restrict__ H1,
                       unsigned* __restrict__ bar){
  int i = blockIdx.x*256 + threadIdx.x;         // 1024 blocks -> 262144
  if (i < 262144) H0[i] = 0;                    // panel 0
  if (i < 65536)  H1[i] = 0;                    // panel 0
  if (i < BAR_DW) bar[i] = 0u;
}

// ---------------- device helpers ----------------

// x[t=g] fp32 -> bf16 into X-bufs (block-local), swizzled like DMA tiles (R12)
__device__ __forceinline__ void xcvt(const MP& p, int g, char* smem){
  const int tid = threadIdx.x;
  const int row = tid >> 3, f0 = (tid & 7) << 5;
  const int m0 = (blockIdx.x >> 6) << 6;
  const float* xs = p.x + (size_t)(m0 + row)*32768 + (size_t)g*256 + f0;
  f32x4 v0,v1,v2,v3,v4,v5,v6,v7;
  PLOADO(v0, xs, 0);  PLOADO(v1, xs, 16); PLOADO(v2, xs, 32); PLOADO(v3, xs, 48);
  PLOADO(v4, xs, 64); PLOADO(v5, xs, 80); PLOADO(v6, xs, 96); PLOADO(v7, xs, 112);
  VMW(0);
  char* xb = smem + LDS_XB + ((f0 >> 7) << 14);
  const int cb = (f0 & 127) >> 3, sw = row & 7;
  union { u16 u[8]; short8 s; } pk;
#define XPK(VA, VB, CC) \
  pk.u[0]=f2b(VA[0]); pk.u[1]=f2b(VA[1]); pk.u[2]=f2b(VA[2]); pk.u[3]=f2b(VA[3]); \
  pk.u[4]=f2b(VB[0]); pk.u[5]=f2b(VB[1]); pk.u[6]=f2b(VB[2]); pk.u[7]=f2b(VB[3]); \
  *(short8*)(xb + row*256 + ((((cb+(CC)) ^ sw))<<4)) = pk.s;
  XPK(v0,v1,0) XPK(v2,v3,1) XPK(v4,v5,2) XPK(v6,v7,3)
#undef XPK
}

// ---------- fused step: tiles 0-1 = x (LDS), 2-9 = h0 (DMA), 10-11 = h1 (DMA)
// Layer0 (all waves, W0 pinned in VGPR for tiles 2-9, streamed for 0-1) and
// Layer1 (waves 0-3, B1 pinned in LDS) consume the SAME staged tiles.
// vmcnt ledger (ops): pre = Bx(8) + S2..S5(8) = 16.
//  t0: VMW(12)[Bx0-3]   t1: VMW(8)[Bx4-7]
//  t2..t7: VMW(6)[S_t done; 3 tiles in flight], issue S(t+4)
//  t8: VMW(6)  t9: VMW(4)  t10: VMW(2)  t11: VMW(0)
// Buffer rotation: tile t -> buf (t-2)&3; S(t+4) (same buf) issued after
// tile t's MFMAs — same pattern validated in R10/R12.
__device__ __forceinline__ void fused(const MP& p, int g, char* smem,
                                      float* c0, float* c1, short8* wp,
                                      bool doP0, bool doP1){
  const int bid = blockIdx.x, tid = threadIdx.x;
  const int grp = bid >> 6, nt = bid & 63;
  const int m0 = grp*64, n0 = nt*64, n1 = nt*16;
  const int lane = tid & 63, wid = tid >> 6;
  const int wm = wid >> 2, wn = wid & 3;
  const int lrow = lane & 15, kgrp = lane >> 4;
  const int sw = lrow & 7;
  const int r8 = lane >> 4, c16 = lane & 15;
  const int row0 = wid*8 + r8, row1 = wid*8 + 4 + r8;
  const char* Hp = (const char*)(p.H0 + (size_t)g*262144);
  const char* h0 = Hp + (size_t)(m0+row0)*2048 + ((c16 ^ (row0 & 7))<<4);
  const char* h1 = Hp + (size_t)(m0+row1)*2048 + ((c16 ^ (row1 & 7))<<4);
  const int gB = (g > 0) ? (g-1) : 0;     // g==0: reads zero panel, p1 off
  const char* HB = (const char*)(p.H1 + (size_t)gB*65536);
  const char* hB0 = HB + (size_t)(m0+row0)*512 + ((c16 ^ (row0 & 7))<<4);
  const char* hB1 = HB + (size_t)(m0+row1)*512 + ((c16 ^ (row1 & 7))<<4);
  char* d0 = smem + wid*2048;
  char* d1 = smem + wid*2048 + 1024;
  const u16* bb = p.W0F + (size_t)nt*81920 + wn*2048 + lane*8;
  const char* b1p = smem + LDS_B1;

  short8 bx0,bx1,bx2,bx3, by0,by1,by2,by3;
  f32x4 acc0 = {0,0,0,0}, acc1 = {0,0,0,0};   // layer0
  f32x4 accp = {0,0,0,0};                     // layer1

#define FS0(T) do{ const int _o = ((T)-2)*256, _bi = (((T)-2)&3)*16384; \
    gll16(h0 + _o, d0 + _bi); gll16(h1 + _o, d1 + _bi); }while(0)
#define FS1(T) do{ const int _o = ((T)-10)*256, _bi = (((T)-2)&3)*16384; \
    gll16(hB0 + _o, d0 + _bi); gll16(hB1 + _o, d1 + _bi); }while(0)
#define F_MFB(BP, B0_,B1_,B2_,B3_) do{ const char* _bp = (BP); short8 _a0,_a1; \
    const int _r0 = (wm*32 + lrow)*256, _r1 = _r0 + 16*256; \
    _a0 = *(const short8*)(_bp + _r0 + (((0+kgrp) ^ sw)<<4)); \
    _a1 = *(const short8*)(_bp + _r1 + (((0+kgrp) ^ sw)<<4)); \
    acc0 = MF(_a0,B0_,acc0); acc1 = MF(_a1,B0_,acc1); \
    _a0 = *(const short8*)(_bp + _r0 + (((4+kgrp) ^ sw)<<4)); \
    _a1 = *(const short8*)(_bp + _r1 + (((4+kgrp) ^ sw)<<4)); \
    acc0 = MF(_a0,B1_,acc0); acc1 = MF(_a1,B1_,acc1); \
    _a0 = *(const short8*)(_bp + _r0 + (((8+kgrp) ^ sw)<<4)); \
    _a1 = *(const short8*)(_bp + _r1 + (((8+kgrp) ^ sw)<<4)); \
    acc0 = MF(_a0,B2_,acc0); acc1 = MF(_a1,B2_,acc1); \
    _a0 = *(const short8*)(_bp + _r0 + (((12+kgrp) ^ sw)<<4)); \
    _a1 = *(const short8*)(_bp + _r1 + (((12+kgrp) ^ sw)<<4)); \
    acc0 = MF(_a0,B3_,acc0); acc1 = MF(_a1,B3_,acc1); }while(0)
#define F_MF1(BUFI, KT1) do{ const char* _bp = smem + (BUFI)*16384; \
    const int _ro = (wid*16 + lrow)*256; short8 _a, _b; \
    _a = *(const short8*)(_bp + _ro + (((0+kgrp) ^ sw)<<4)); \
    _b = *(const short8*)(b1p + (((KT1)*4+0)<<10) + lane*16); accp = MF(_a,_b,accp); \
    _a = *(const short8*)(_bp + _ro + (((4+kgrp) ^ sw)<<4)); \
    _b = *(const short8*)(b1p + (((KT1)*4+1)<<10) + lane*16); accp = MF(_a,_b,accp); \
    _a = *(const short8*)(_bp + _ro + (((8+kgrp) ^ sw)<<4)); \
    _b = *(const short8*)(b1p + (((KT1)*4+2)<<10) + lane*16); accp = MF(_a,_b,accp); \
    _a = *(const short8*)(_bp + _ro + (((12+kgrp) ^ sw)<<4)); \
    _b = *(const short8*)(b1p + (((KT1)*4+3)<<10) + lane*16); accp = MF(_a,_b,accp); }while(0)

  // prologue: stream x-weights + stage first 4 h0 tiles
  { const u16* _s = bb;                     // tile 0
    PLOADO(bx0,_s,0); PLOADO(bx1,_s,1024); PLOADO(bx2,_s,2048); PLOADO(bx3,_s,3072); }
  { const u16* _s = bb + 8192;              // tile 1
    PLOADO(by0,_s,0); PLOADO(by1,_s,1024); PLOADO(by2,_s,2048); PLOADO(by3,_s,3072); }
  FS0(2); FS0(3); FS0(4); FS0(5);

  VMW(12); BAR; if (doP0) F_MFB(smem + LDS_XB,         bx0,bx1,bx2,bx3);
  VMW(8);  BAR; if (doP0) F_MFB(smem + LDS_XB + 16384, by0,by1,by2,by3);
  VMW(6); BAR; if (doP0) F_MFB(smem,         wp[0], wp[1], wp[2], wp[3]);
               if (doP1 && wid < 4) F_MF1(0, 0);  FS0(6);
  VMW(6); BAR; if (doP0) F_MFB(smem + 16384, wp[4], wp[5], wp[6], wp[7]);
               if (doP1 && wid < 4) F_MF1(1, 1);  FS0(7);
  VMW(6); BAR; if (doP0) F_MFB(smem + 32768, wp[8], wp[9], wp[10], wp[11]);
               if (doP1 && wid < 4) F_MF1(2, 2);  FS0(8);
  VMW(6); BAR; if (doP0) F_MFB(smem + 49152, wp[12], wp[13], wp[14], wp[15]);
               if (doP1 && wid < 4) F_MF1(3, 3);  FS0(9);
  VMW(6); BAR; if (doP0) F_MFB(smem,         wp[16], wp[17], wp[18], wp[19]);
               if (doP1 && wid < 4) F_MF1(0, 4);  FS1(10);
  VMW(6); BAR; if (doP0) F_MFB(smem + 16384, wp[20], wp[21], wp[22], wp[23]);
               if (doP1 && wid < 4) F_MF1(1, 5);  FS1(11);
  VMW(6); BAR; if (doP0) F_MFB(smem + 32768, wp[24], wp[25], wp[26], wp[27]);
               if (doP1 && wid < 4) F_MF1(2, 6);
  VMW(4); BAR; if (doP0) F_MFB(smem + 49152, wp[28], wp[29], wp[30], wp[31]);
               if (doP1 && wid < 4) F_MF1(3, 7);
  VMW(2); BAR; if (doP1 && wid < 4) F_MF1(0, 8);
  VMW(0); BAR; if (doP1 && wid < 4) F_MF1(1, 9);

  // ---- merged epilogue: gl0 at smem+0 ([64][68] f32), gl1 at +20480 ([64][20])
  __syncthreads();
  float* gl0 = (float*)smem;
  float* gl1 = (float*)(smem + 20480);
  if (doP0) {
#pragma unroll
    for (int r = 0; r < 4; ++r) {
      gl0[(wm*32      + kgrp*4 + r)*68 + wn*16 + lrow] = acc0[r];
      gl0[(wm*32 + 16 + kgrp*4 + r)*68 + wn*16 + lrow] = acc1[r];
    }
  }
  if (doP1 && wid < 4) {
#pragma unroll
    for (int r = 0; r < 4; ++r)
      gl1[(wid*16 + kgrp*4 + r)*20 + lrow] = accp[r];
  }
  __syncthreads();
  if (doP0) {
    u16* H0w = p.H0 + (size_t)(g+1)*262144;
    int bl = tid >> 3, hp = tid & 7;
    int b = m0 + bl, h = nt*16 + hp*2;
    float hn[2];
#pragma unroll
    for (int q = 0; q < 2; ++q) {
      int col = (hp*2 + q)*4;
      float gi = gl0[bl*68 + col+0] + p.b0[n0 + col+0];
      float gf = gl0[bl*68 + col+1] + p.b0[n0 + col+1];
      float go = gl0[bl*68 + col+2] + p.b0[n0 + col+2];
      float gc = gl0[bl*68 + col+3] + p.b0[n0 + col+3];
      float cn = sigm(gf)*c0[q] + sigm(gi)*tanh_(gc);
      hn[q] = sigm(go)*tanh_(cn);
      c0[q] = cn;
      if (g == TS-1) {
        p.out[OFF_H0 + (size_t)b*1024 + h + q] = hn[q];
        p.out[OFF_C0 + (size_t)b*1024 + h + q] = cn;
      }
    }
    ast32(H0w + (size_t)b*1024 + h, (u32)f2b(hn[0]) | ((u32)f2b(hn[1]) << 16));
  }
  if (doP1 && tid < 128) {
    u16* H1w = p.H1 + (size_t)g*65536;
    int bl = tid >> 1, hp = tid & 1;
    int b = m0 + bl, h = nt*4 + hp*2;
    float hn[2];
#pragma unroll
    for (int q = 0; q < 2; ++q) {
      int col = (hp*2 + q)*4;
      float gi = gl1[bl*20 + col+0] + p.b1[n1 + col+0];
      float gf = gl1[bl*20 + col+1] + p.b1[n1 + col+1];
      float go = gl1[bl*20 + col+2] + p.b1[n1 + col+2];
      float gc = gl1[bl*20 + col+3] + p.b1[n1 + col+3];
      float cn = sigm(gf)*c1[q] + sigm(gi)*tanh_(gc);
      hn[q] = sigm(go)*tanh_(cn);
      c1[q] = cn;
      if (g == TS) {
        p.out[OFF_H1 + (size_t)b*256 + h + q] = hn[q];
        p.out[OFF_C1 + (size_t)b*256 + h + q] = cn;
      }
    }
    ast32(H1w + (size_t)b*256 + h, (u32)f2b(hn[0]) | ((u32)f2b(hn[1]) << 16));
  }
}

// ---------------- main cooperative kernel ----------------
__global__ __launch_bounds__(NT, 1) void k_main(MP p){
  __shared__ __attribute__((aligned(16))) char smem[LDS_SZ];
  float c0[2] = {0.f, 0.f};
  float c1[2] = {0.f, 0.f};
  short8 wp[32];                        // pinned W0 frags, tiles 2-9 (static-indexed)
  const int bid = blockIdx.x, tid = threadIdx.x;
  const int grp = bid >> 6, j = bid & 63;
  const int lane = tid & 63, wid = tid >> 6;
  unsigned* flags = p.bar;
  unsigned* rel   = p.bar + 4096 + grp*16;

  // pin B1 slice in LDS (40 KB) — once
  {
    const char* wsrc = (const char*)p.W1F + (size_t)j*40960 + lane*16;
#pragma unroll
    for (int q = 0; q < 5; ++q) {
      int f = wid*5 + q;
      gll16(wsrc + f*1024, smem + LDS_B1 + f*1024);
    }
    VMW(0);
  }
  // pin W0 frags (tiles 2-9) in VGPRs — once
  {
    const u16* bb = p.W0F + (size_t)j*81920 + (wid & 3)*2048 + lane*8;
#define LDW(T) do{ const u16* _s = bb + (size_t)(T)*8192; \
    PLOADO(wp[((T)-2)*4+0],_s,0); PLOADO(wp[((T)-2)*4+1],_s,1024); \
    PLOADO(wp[((T)-2)*4+2],_s,2048); PLOADO(wp[((T)-2)*4+3],_s,3072); }while(0)
    LDW(2); LDW(3); LDW(4); LDW(5); LDW(6); LDW(7); LDW(8); LDW(9);
#undef LDW
    VMW(0);
  }

  xcvt(p, 0, smem);
  __syncthreads();
  fused(p, 0, smem, c0, c1, wp, true, false);   // layer0 t=0 only

  for (int g = 1; g <= TS; ++g) {
    // arrive (drains sc1 h-stores), shadow-convert x[g], wait release
    __syncthreads();
    if (j == 0) {
      if (tid >= 1 && tid < 64) {
        while (__hip_atomic_load(&flags[(grp*64 + tid)*16], __ATOMIC_RELAXED,
                                 __HIP_MEMORY_SCOPE_AGENT) < (unsigned)g)
          __builtin_amdgcn_s_sleep(1);
      }
      __syncthreads();
      if (tid == 0)
        __hip_atomic_store(rel, (unsigned)g, __ATOMIC_RELAXED, __HIP_MEMORY_SCOPE_AGENT);
    } else {
      if (tid == 0)
        __hip_atomic_store(&flags[bid*16], (unsigned)g, __ATOMIC_RELAXED,
                           __HIP_MEMORY_SCOPE_AGENT);
    }
    if (g < TS) xcvt(p, g, smem);
    if (j != 0 && tid == 0) {
      while (__hip_atomic_load(rel, __ATOMIC_RELAXED, __HIP_MEMORY_SCOPE_AGENT) < (unsigned)g)
        __builtin_amdgcn_s_sleep(1);
    }
    __syncthreads();
    fused(p, g, smem, c0, c1, wp, g < TS, true);
  }
}

// ---------------- final projection (reads H1seq bf16) ----------------
__global__ void k_final_seq(const u16* __restrict__ H1seq, const float* __restrict__ Wout,
                            const float* __restrict__ bout, float* __restrict__ out){
  __shared__ float Ws[1536];
  __shared__ float bs[12];
  for (int i = threadIdx.x; i < 1536; i += 256) Ws[i] = Wout[i];
  if (threadIdx.x < 12) bs[threadIdx.x] = bout[threadIdx.x];
  __syncthreads();
  int gid = blockIdx.x*256 + threadIdx.x;
  int b = gid >> 8, ii = gid & 255;
  const u16* src = H1seq + (size_t)((ii >> 1) + 1)*65536 + b*256 + (ii & 1)*128;
  float acc[12];
#pragma unroll
  for (int k = 0; k < 12; ++k) acc[k] = bs[k];
  for (int jj = 0; jj < 128; jj += 8) {
    union { u16 u[8]; short8 v; } pk;
    pk.v = *(const short8*)&src[jj];
#pragma unroll
    for (int e = 0; e < 8; ++e) {
      float f = b2f(pk.u[e]);
#pragma unroll
      for (int k = 0; k < 12; ++k) acc[k] += f*Ws[(jj+e)*12+k];
    }
  }
  float* dst = out + (size_t)b*3072 + ii*12;
#pragma unroll
  for (int k = 0; k < 12; ++k) dst[k] = acc[k];
}

extern "C" void kernel_launch(void* const* d_in, const int* in_sizes, int n_in,
                              void* d_out, int out_size, void* d_ws, size_t ws_size,
                              hipStream_t stream) {
  if (ws_size < (size_t)WS_NEED) return;   // fail visibly if ws too small
  const float* x    = (const float*)d_in[0];
  const float* Wx0  = (const float*)d_in[1];
  const float* bx0  = (const float*)d_in[2];
  const float* Wh0  = (const float*)d_in[3];
  const float* bh0  = (const float*)d_in[4];
  const float* Wx1  = (const float*)d_in[5];
  const float* bx1  = (const float*)d_in[6];
  const float* Wh1  = (const float*)d_in[7];
  const float* bh1  = (const float*)d_in[8];
  const float* Wout = (const float*)d_in[9];
  const float* bout = (const float*)d_in[10];

  char* ws = (char*)d_ws;
  u16*   W0F  = (u16*)  (ws + WSO_W0F);
  u16*   W1F  = (u16*)  (ws + WSO_W1F);
  float* b0   = (float*)(ws + WSO_B0);
  float* b1   = (float*)(ws + WSO_B1);
  unsigned* bar = (unsigned*)(ws + WSO_BAR);
  u16*   H0   = (u16*)  (ws + WSO_H0);
  u16*   H1   = (u16*)  (ws + WSO_H1);
  float* out = (float*)d_out;

  k_packF0<<<2560, 256, 0, stream>>>(Wx0, Wh0, W0F);
  k_packF1<<<640, 256, 0, stream>>>(Wx1, Wh1, W1F);
  k_bias<<<16, 256, 0, stream>>>(bx0, bh0, bx1, bh1, b0, b1);
  k_init<<<1024, 256, 0, stream>>>(H0, H1, bar);

  MP p;
  p.x = x; p.W0F = W0F; p.W1F = W1F; p.b0 = b0; p.b1 = b1;
  p.H0 = H0; p.H1 = H1; p.out = out; p.bar = bar;
  void* kargs[] = { (void*)&p };
  hipLaunchCooperativeKernel((const void*)k_main, dim3(NB), dim3(NT), kargs, 0, stream);

  k_final_seq<<<256, 256, 0, stream>>>(H1, Wout, bout, out);
}